// Round 1
// baseline (2005.232 us; speedup 1.0000x reference)
//
#include <hip/hip_runtime.h>

// Problem constants (from setup_inputs)
#define NH    8      // heads
#define BB    16     // batch
#define SQ    1024   // query seq len
#define CC    1280   // channels
#define SENC  77     // encoder seq len
#define CENC  1024   // encoder channels
#define DH    160    // head dim
#define RANK  4

// ---------------------------------------------------------------------------
// Weight fold: Weff[n][k] = W[n][k] + sum_r up[n][r] * down[r][k]
// (LORA_SCALE = 1, so lora(x) = x @ (up@down)^T folds into the weight.)
// ---------------------------------------------------------------------------
__global__ void fold_kernel(const float* __restrict__ W,
                            const float* __restrict__ up,
                            const float* __restrict__ down,
                            float* __restrict__ out, int N, int K) {
    int idx4 = blockIdx.x * blockDim.x + threadIdx.x;
    int total4 = (N * K) >> 2;
    if (idx4 >= total4) return;
    int i = idx4 << 2;
    int n = i / K;
    int kk = i - n * K;
    float4 acc = *(const float4*)(W + i);
#pragma unroll
    for (int r = 0; r < RANK; ++r) {
        float u = up[n * RANK + r];
        float4 dv = *(const float4*)(down + (size_t)r * K + kk);
        acc.x += u * dv.x; acc.y += u * dv.y;
        acc.z += u * dv.z; acc.w += u * dv.w;
    }
    *(float4*)(out + i) = acc;
}

// ---------------------------------------------------------------------------
// C[m][n] = sum_k A[m][k] * W[n][k]  (+ bias[n])     A:[M,K]  W:[N,K]  both row-major
// 128x128 tile, BK=16, 256 threads, 8x8 microtile.
// LDS k-major (As[k][m]) so microtile reads are float4; pad 132 keeps all
// ds_read_b128 at <=2-way bank aliasing (free) and staging writes at 2-way.
// N must be a multiple of 128 (true here: N=1280). M is guarded.
// ---------------------------------------------------------------------------
#define BM 128
#define BN 128
#define BK 16
#define LDP (BM + 4)

__global__ __launch_bounds__(256) void gemm_nt_kernel(
    const float* __restrict__ A, const float* __restrict__ W,
    const float* __restrict__ bias, float* __restrict__ C,
    int M, int N, int K) {
    __shared__ float As[BK][LDP];
    __shared__ float Ws[BK][LDP];
    const int tid = threadIdx.x;
    const int tx = tid & 15;
    const int ty = tid >> 4;
    const int m0 = blockIdx.y * BM;
    const int n0 = blockIdx.x * BN;

    float acc[8][8];
#pragma unroll
    for (int i = 0; i < 8; ++i)
#pragma unroll
        for (int j = 0; j < 8; ++j) acc[i][j] = 0.f;

    const int sm  = tid >> 2;        // 0..63 : row within half-tile
    const int skg = (tid & 3) * 4;   // 0,4,8,12 : k-group

    for (int k0 = 0; k0 < K; k0 += BK) {
#pragma unroll
        for (int ss = 0; ss < 2; ++ss) {
            int m = sm + ss * 64;
            float4 av = make_float4(0.f, 0.f, 0.f, 0.f);
            if (m0 + m < M)
                av = *(const float4*)(A + (size_t)(m0 + m) * K + k0 + skg);
            As[skg + 0][m] = av.x; As[skg + 1][m] = av.y;
            As[skg + 2][m] = av.z; As[skg + 3][m] = av.w;
            float4 wv = *(const float4*)(W + (size_t)(n0 + m) * K + k0 + skg);
            Ws[skg + 0][m] = wv.x; Ws[skg + 1][m] = wv.y;
            Ws[skg + 2][m] = wv.z; Ws[skg + 3][m] = wv.w;
        }
        __syncthreads();
#pragma unroll
        for (int kk = 0; kk < BK; ++kk) {
            float4 a0 = *(const float4*)&As[kk][ty * 4];
            float4 a1 = *(const float4*)&As[kk][64 + ty * 4];
            float4 b0 = *(const float4*)&Ws[kk][tx * 4];
            float4 b1 = *(const float4*)&Ws[kk][64 + tx * 4];
            float a[8] = {a0.x, a0.y, a0.z, a0.w, a1.x, a1.y, a1.z, a1.w};
            float b[8] = {b0.x, b0.y, b0.z, b0.w, b1.x, b1.y, b1.z, b1.w};
#pragma unroll
            for (int i = 0; i < 8; ++i)
#pragma unroll
                for (int j = 0; j < 8; ++j)
                    acc[i][j] += a[i] * b[j];
        }
        __syncthreads();
    }

    float bvals[8] = {0.f, 0.f, 0.f, 0.f, 0.f, 0.f, 0.f, 0.f};
    if (bias != nullptr) {
#pragma unroll
        for (int jh = 0; jh < 2; ++jh) {
            float4 bv = *(const float4*)(bias + n0 + jh * 64 + tx * 4);
            bvals[jh * 4 + 0] = bv.x; bvals[jh * 4 + 1] = bv.y;
            bvals[jh * 4 + 2] = bv.z; bvals[jh * 4 + 3] = bv.w;
        }
    }
#pragma unroll
    for (int ih = 0; ih < 2; ++ih) {
#pragma unroll
        for (int i = 0; i < 4; ++i) {
            int m = m0 + ih * 64 + ty * 4 + i;
            if (m >= M) continue;
#pragma unroll
            for (int jh = 0; jh < 2; ++jh) {
                int n = n0 + jh * 64 + tx * 4;
                float4 o;
                o.x = acc[ih * 4 + i][jh * 4 + 0] + bvals[jh * 4 + 0];
                o.y = acc[ih * 4 + i][jh * 4 + 1] + bvals[jh * 4 + 1];
                o.z = acc[ih * 4 + i][jh * 4 + 2] + bvals[jh * 4 + 2];
                o.w = acc[ih * 4 + i][jh * 4 + 3] + bvals[jh * 4 + 3];
                *(float4*)(C + (size_t)m * N + n) = o;
            }
        }
    }
}

// ---------------------------------------------------------------------------
// Attention: one thread per query row, one block per (b, h, chunk-of-256-queries).
// Scores p[77] kept in registers (all j-loops fully unrolled -> static indexing).
// K/V read via all-lanes-same-address global loads (wave broadcast, L2-resident
// 98KB/head tile) -- no LDS needed. Output written in place over q (disjoint
// per-thread row slices).
// ---------------------------------------------------------------------------
__global__ __launch_bounds__(256) void attn_kernel(
    const float* __restrict__ q, const float* __restrict__ k,
    const float* __restrict__ v, float* __restrict__ o) {
    const int tid = threadIdx.x;
    const int chunk = blockIdx.x & 3;
    const int bh = blockIdx.x >> 2;
    const int h = bh % NH;
    const int b = bh / NH;
    const int s = chunk * 256 + tid;
    const float scale = 0.07905694150420949f;  // 1/sqrt(160)

    const float* qrow  = q + ((size_t)(b * SQ + s)) * CC + h * DH;
    const float* kbase = k + ((size_t)b * SENC) * CC + h * DH;
    const float* vbase = v + ((size_t)b * SENC) * CC + h * DH;

    float p[SENC];
#pragma unroll
    for (int j = 0; j < SENC; ++j) p[j] = 0.f;

    for (int d4 = 0; d4 < DH; d4 += 4) {
        float4 qv = *(const float4*)(qrow + d4);
#pragma unroll
        for (int j = 0; j < SENC; ++j) {
            float4 kv = *(const float4*)(kbase + (size_t)j * CC + d4);
            p[j] += qv.x * kv.x + qv.y * kv.y + qv.z * kv.z + qv.w * kv.w;
        }
    }

    float mx = -1e30f;
#pragma unroll
    for (int j = 0; j < SENC; ++j) { p[j] *= scale; mx = fmaxf(mx, p[j]); }
    float sum = 0.f;
#pragma unroll
    for (int j = 0; j < SENC; ++j) { p[j] = __expf(p[j] - mx); sum += p[j]; }
    float inv = 1.f / sum;
#pragma unroll
    for (int j = 0; j < SENC; ++j) p[j] *= inv;

    float* orow = o + ((size_t)(b * SQ + s)) * CC + h * DH;
    for (int d4 = 0; d4 < DH; d4 += 4) {
        float4 acc = make_float4(0.f, 0.f, 0.f, 0.f);
#pragma unroll
        for (int j = 0; j < SENC; ++j) {
            float4 vv = *(const float4*)(vbase + (size_t)j * CC + d4);
            acc.x += p[j] * vv.x; acc.y += p[j] * vv.y;
            acc.z += p[j] * vv.z; acc.w += p[j] * vv.w;
        }
        *(float4*)(orow + d4) = acc;
    }
}

// ---------------------------------------------------------------------------
// Workspace layout (floats):
//   Wq_eff 1638400 | Wk_eff 1310720 | Wv_eff 1310720 | Wo_eff 1638400
//   q_ws 20971520 (reused in-place as attention output) | k_ws 1576960 | v_ws 1576960
// Total = 30,023,680 floats = 120.1 MB
// ---------------------------------------------------------------------------
extern "C" void kernel_launch(void* const* d_in, const int* in_sizes, int n_in,
                              void* d_out, int out_size, void* d_ws, size_t ws_size,
                              hipStream_t stream) {
    const float* hidden = (const float*)d_in[0];
    const float* enc    = (const float*)d_in[1];
    const float* Wq     = (const float*)d_in[2];
    const float* Wk     = (const float*)d_in[3];
    const float* Wv     = (const float*)d_in[4];
    const float* Wo     = (const float*)d_in[5];
    const float* bo     = (const float*)d_in[6];
    const float* q_down = (const float*)d_in[7];
    const float* q_up   = (const float*)d_in[8];
    const float* k_down = (const float*)d_in[9];
    const float* k_up   = (const float*)d_in[10];
    const float* v_down = (const float*)d_in[11];
    const float* v_up   = (const float*)d_in[12];
    const float* o_down = (const float*)d_in[13];
    const float* o_up   = (const float*)d_in[14];

    float* ws      = (float*)d_ws;
    float* Wq_eff  = ws;
    float* Wk_eff  = Wq_eff + 1638400;
    float* Wv_eff  = Wk_eff + 1310720;
    float* Wo_eff  = Wv_eff + 1310720;
    float* q_ws    = Wo_eff + 1638400;
    float* k_ws    = q_ws + 20971520;
    float* v_ws    = k_ws + 1576960;

    const int M1 = BB * SQ;    // 16384
    const int M2 = BB * SENC;  // 1232

    // Fold LoRA rank-4 updates into the weights.
    fold_kernel<<<1600, 256, 0, stream>>>(Wq, q_up, q_down, Wq_eff, CC, CC);
    fold_kernel<<<1280, 256, 0, stream>>>(Wk, k_up, k_down, Wk_eff, CC, CENC);
    fold_kernel<<<1280, 256, 0, stream>>>(Wv, v_up, v_down, Wv_eff, CC, CENC);
    fold_kernel<<<1600, 256, 0, stream>>>(Wo, o_up, o_down, Wo_eff, CC, CC);

    dim3 blk(256);
    // q = hidden @ Wq_eff^T
    gemm_nt_kernel<<<dim3(CC / BN, M1 / BM), blk, 0, stream>>>(
        hidden, Wq_eff, nullptr, q_ws, M1, CC, CC);
    // k/v = enc @ W{k,v}_eff^T
    gemm_nt_kernel<<<dim3(CC / BN, (M2 + BM - 1) / BM), blk, 0, stream>>>(
        enc, Wk_eff, nullptr, k_ws, M2, CC, CENC);
    gemm_nt_kernel<<<dim3(CC / BN, (M2 + BM - 1) / BM), blk, 0, stream>>>(
        enc, Wv_eff, nullptr, v_ws, M2, CC, CENC);
    // attention, output in place over q_ws
    attn_kernel<<<BB * NH * 4, blk, 0, stream>>>(q_ws, k_ws, v_ws, q_ws);
    // out = attn @ Wo_eff^T + bo
    gemm_nt_kernel<<<dim3(CC / BN, M1 / BM), blk, 0, stream>>>(
        q_ws, Wo_eff, bo, (float*)d_out, M1, CC, CC);
}

// Round 2
// 1287.578 us; speedup vs baseline: 1.5574x; 1.5574x over previous
//
#include <hip/hip_runtime.h>

// Problem constants
#define NH    8
#define BB    16
#define SQ    1024
#define CC    1280
#define SENC  77
#define CENC  1024
#define DH    160
#define RANK  4

typedef __attribute__((ext_vector_type(8))) short bf16x8;
typedef __attribute__((ext_vector_type(4))) float f32x4;

// ---------------------------------------------------------------------------
// fp32 -> bf16 hi/lo split (truncation; hi+lo captures ~16 mantissa bits)
// ---------------------------------------------------------------------------
__device__ inline void split_bf16(float a, unsigned short& hi, unsigned short& lo) {
    unsigned u = __float_as_uint(a);
    hi = (unsigned short)(u >> 16);
    float fhi = __uint_as_float(u & 0xffff0000u);
    float r = a - fhi;
    lo = (unsigned short)(__float_as_uint(r) >> 16);
}

// ---------------------------------------------------------------------------
// Weight fold (fp32 out): Weff = W + up@down   (for Wk, Wv)
// ---------------------------------------------------------------------------
__global__ void fold_kernel(const float* __restrict__ W,
                            const float* __restrict__ up,
                            const float* __restrict__ down,
                            float* __restrict__ out, int N, int K) {
    int idx4 = blockIdx.x * blockDim.x + threadIdx.x;
    int total4 = (N * K) >> 2;
    if (idx4 >= total4) return;
    int i = idx4 << 2;
    int n = i / K;
    int kk = i - n * K;
    float4 acc = *(const float4*)(W + i);
#pragma unroll
    for (int r = 0; r < RANK; ++r) {
        float u = up[n * RANK + r];
        float4 dv = *(const float4*)(down + (size_t)r * K + kk);
        acc.x += u * dv.x; acc.y += u * dv.y;
        acc.z += u * dv.z; acc.w += u * dv.w;
    }
    *(float4*)(out + i) = acc;
}

// ---------------------------------------------------------------------------
// Weight fold + bf16 hi/lo split (for Wq, Wo)
// ---------------------------------------------------------------------------
__global__ void fold_split_kernel(const float* __restrict__ W,
                                  const float* __restrict__ up,
                                  const float* __restrict__ down,
                                  unsigned short* __restrict__ ohi,
                                  unsigned short* __restrict__ olo,
                                  int N, int K) {
    int idx4 = blockIdx.x * blockDim.x + threadIdx.x;
    int total4 = (N * K) >> 2;
    if (idx4 >= total4) return;
    int i = idx4 << 2;
    int n = i / K;
    int kk = i - n * K;
    float4 acc = *(const float4*)(W + i);
#pragma unroll
    for (int r = 0; r < RANK; ++r) {
        float u = up[n * RANK + r];
        float4 dv = *(const float4*)(down + (size_t)r * K + kk);
        acc.x += u * dv.x; acc.y += u * dv.y;
        acc.z += u * dv.z; acc.w += u * dv.w;
    }
    unsigned short h0, h1, h2, h3, l0, l1, l2, l3;
    split_bf16(acc.x, h0, l0); split_bf16(acc.y, h1, l1);
    split_bf16(acc.z, h2, l2); split_bf16(acc.w, h3, l3);
    int2 hv, lv;
    hv.x = (int)((unsigned)h0 | ((unsigned)h1 << 16));
    hv.y = (int)((unsigned)h2 | ((unsigned)h3 << 16));
    lv.x = (int)((unsigned)l0 | ((unsigned)l1 << 16));
    lv.y = (int)((unsigned)l2 | ((unsigned)l3 << 16));
    *(int2*)(ohi + i) = hv;
    *(int2*)(olo + i) = lv;
}

// ---------------------------------------------------------------------------
// Activation fp32 -> bf16 hi/lo split (for hidden_states)
// ---------------------------------------------------------------------------
__global__ void split_kernel(const float* __restrict__ x,
                             unsigned short* __restrict__ ohi,
                             unsigned short* __restrict__ olo, int total4) {
    int idx4 = blockIdx.x * blockDim.x + threadIdx.x;
    if (idx4 >= total4) return;
    int i = idx4 << 2;
    float4 a = *(const float4*)(x + i);
    unsigned short h0, h1, h2, h3, l0, l1, l2, l3;
    split_bf16(a.x, h0, l0); split_bf16(a.y, h1, l1);
    split_bf16(a.z, h2, l2); split_bf16(a.w, h3, l3);
    int2 hv, lv;
    hv.x = (int)((unsigned)h0 | ((unsigned)h1 << 16));
    hv.y = (int)((unsigned)h2 | ((unsigned)h3 << 16));
    lv.x = (int)((unsigned)l0 | ((unsigned)l1 << 16));
    lv.y = (int)((unsigned)l2 | ((unsigned)l3 << 16));
    *(int2*)(ohi + i) = hv;
    *(int2*)(olo + i) = lv;
}

// ---------------------------------------------------------------------------
// MFMA split-bf16 GEMM: C[m][n] = sum_k A[m][k]*W[n][k] (+bias[n]), fp32-accurate
// via A_hi*W_hi + A_hi*W_lo + A_lo*W_hi. 128x128 tile, BK=32 bf16, 4 waves,
// each wave 64x64 (4x4 frags of 16x16x32). global_load_lds(16B) staging,
// linear LDS (m97 structure). Requires M%128==0, N%128==0, K%32==0.
// ---------------------------------------------------------------------------
#define GBM 128
#define GBN 128
#define GBK 32

__device__ inline void async_load16(const void* gsrc, void* lds_dst) {
    __builtin_amdgcn_global_load_lds(
        (const __attribute__((address_space(1))) void*)gsrc,
        (__attribute__((address_space(3))) void*)lds_dst, 16, 0, 0);
}

__global__ __launch_bounds__(256) void gemm_bf16x3_kernel(
    const unsigned short* __restrict__ A_hi, const unsigned short* __restrict__ A_lo,
    const unsigned short* __restrict__ W_hi, const unsigned short* __restrict__ W_lo,
    const float* __restrict__ bias, float* __restrict__ C,
    int M, int N, int K) {
    // lds[0]=A_hi  [1]=A_lo  [2]=W_hi  [3]=W_lo   (each 128 rows x 32 bf16)
    __shared__ __align__(16) unsigned short lds[4][GBM][GBK];
    const int tid  = threadIdx.x;
    const int wave = tid >> 6;
    const int lane = tid & 63;
    const int m0 = blockIdx.y * GBM;
    const int n0 = blockIdx.x * GBN;
    const int wr = wave >> 1, wc = wave & 1;

    f32x4 zero = {0.f, 0.f, 0.f, 0.f};
    f32x4 acc[4][4];
#pragma unroll
    for (int i = 0; i < 4; ++i)
#pragma unroll
        for (int j = 0; j < 4; ++j) acc[i][j] = zero;

    // staging geometry: tile of 8192B = 8 chunks of 1024B (16 rows each);
    // wave w stages chunks 2w and 2w+1 of each of the 4 tiles.
    const int c0 = wave * 2, c1 = wave * 2 + 1;
    const int rr = lane >> 2;           // row within 16-row chunk
    const int kc = (lane & 3) * 8;      // k element offset (8 bf16 = 16B)
    const unsigned short* pAh0 = A_hi + (size_t)(m0 + c0 * 16 + rr) * K + kc;
    const unsigned short* pAh1 = A_hi + (size_t)(m0 + c1 * 16 + rr) * K + kc;
    const unsigned short* pAl0 = A_lo + (size_t)(m0 + c0 * 16 + rr) * K + kc;
    const unsigned short* pAl1 = A_lo + (size_t)(m0 + c1 * 16 + rr) * K + kc;
    const unsigned short* pWh0 = W_hi + (size_t)(n0 + c0 * 16 + rr) * K + kc;
    const unsigned short* pWh1 = W_hi + (size_t)(n0 + c1 * 16 + rr) * K + kc;
    const unsigned short* pWl0 = W_lo + (size_t)(n0 + c0 * 16 + rr) * K + kc;
    const unsigned short* pWl1 = W_lo + (size_t)(n0 + c1 * 16 + rr) * K + kc;

    for (int k0 = 0; k0 < K; k0 += GBK) {
        async_load16(pAh0 + k0, &lds[0][c0 * 16][0]);
        async_load16(pAh1 + k0, &lds[0][c1 * 16][0]);
        async_load16(pAl0 + k0, &lds[1][c0 * 16][0]);
        async_load16(pAl1 + k0, &lds[1][c1 * 16][0]);
        async_load16(pWh0 + k0, &lds[2][c0 * 16][0]);
        async_load16(pWh1 + k0, &lds[2][c1 * 16][0]);
        async_load16(pWl0 + k0, &lds[3][c0 * 16][0]);
        async_load16(pWl1 + k0, &lds[3][c1 * 16][0]);
        __syncthreads();

        bf16x8 ah[4], al[4], bh[4], bl[4];
        const int fr = lane & 15;        // row/col within frag
        const int kb = (lane >> 4) * 8;  // k group (same mapping for A and B)
#pragma unroll
        for (int i = 0; i < 4; ++i) {
            ah[i] = *(const bf16x8*)&lds[0][wr * 64 + i * 16 + fr][kb];
            al[i] = *(const bf16x8*)&lds[1][wr * 64 + i * 16 + fr][kb];
            bh[i] = *(const bf16x8*)&lds[2][wc * 64 + i * 16 + fr][kb];
            bl[i] = *(const bf16x8*)&lds[3][wc * 64 + i * 16 + fr][kb];
        }
#pragma unroll
        for (int i = 0; i < 4; ++i)
#pragma unroll
            for (int j = 0; j < 4; ++j) {
                acc[i][j] = __builtin_amdgcn_mfma_f32_16x16x32_bf16(ah[i], bh[j], acc[i][j], 0, 0, 0);
                acc[i][j] = __builtin_amdgcn_mfma_f32_16x16x32_bf16(ah[i], bl[j], acc[i][j], 0, 0, 0);
                acc[i][j] = __builtin_amdgcn_mfma_f32_16x16x32_bf16(al[i], bh[j], acc[i][j], 0, 0, 0);
            }
        __syncthreads();
    }

    // epilogue: C/D layout col=lane&15, row=(lane>>4)*4+reg  [m89-verified]
    const int fc = lane & 15;
    const int fr4 = (lane >> 4) * 4;
#pragma unroll
    for (int j = 0; j < 4; ++j) {
        int col = n0 + wc * 64 + j * 16 + fc;
        float bv = bias ? bias[col] : 0.f;
#pragma unroll
        for (int i = 0; i < 4; ++i) {
            int row = m0 + wr * 64 + i * 16 + fr4;
#pragma unroll
            for (int r = 0; r < 4; ++r)
                C[(size_t)(row + r) * N + col] = acc[i][j][r] + bv;
        }
    }
}

// ---------------------------------------------------------------------------
// fp32 tiled GEMM (unchanged, used for the small k/v projections)
// ---------------------------------------------------------------------------
#define BM 128
#define BN 128
#define BK 16
#define LDP (BM + 4)

__global__ __launch_bounds__(256) void gemm_nt_kernel(
    const float* __restrict__ A, const float* __restrict__ W,
    const float* __restrict__ bias, float* __restrict__ C,
    int M, int N, int K) {
    __shared__ float As[BK][LDP];
    __shared__ float Ws[BK][LDP];
    const int tid = threadIdx.x;
    const int tx = tid & 15;
    const int ty = tid >> 4;
    const int m0 = blockIdx.y * BM;
    const int n0 = blockIdx.x * BN;

    float acc[8][8];
#pragma unroll
    for (int i = 0; i < 8; ++i)
#pragma unroll
        for (int j = 0; j < 8; ++j) acc[i][j] = 0.f;

    const int sm  = tid >> 2;
    const int skg = (tid & 3) * 4;

    for (int k0 = 0; k0 < K; k0 += BK) {
#pragma unroll
        for (int ss = 0; ss < 2; ++ss) {
            int m = sm + ss * 64;
            float4 av = make_float4(0.f, 0.f, 0.f, 0.f);
            if (m0 + m < M)
                av = *(const float4*)(A + (size_t)(m0 + m) * K + k0 + skg);
            As[skg + 0][m] = av.x; As[skg + 1][m] = av.y;
            As[skg + 2][m] = av.z; As[skg + 3][m] = av.w;
            float4 wv = *(const float4*)(W + (size_t)(n0 + m) * K + k0 + skg);
            Ws[skg + 0][m] = wv.x; Ws[skg + 1][m] = wv.y;
            Ws[skg + 2][m] = wv.z; Ws[skg + 3][m] = wv.w;
        }
        __syncthreads();
#pragma unroll
        for (int kk = 0; kk < BK; ++kk) {
            float4 a0 = *(const float4*)&As[kk][ty * 4];
            float4 a1 = *(const float4*)&As[kk][64 + ty * 4];
            float4 b0 = *(const float4*)&Ws[kk][tx * 4];
            float4 b1 = *(const float4*)&Ws[kk][64 + tx * 4];
            float a[8] = {a0.x, a0.y, a0.z, a0.w, a1.x, a1.y, a1.z, a1.w};
            float b[8] = {b0.x, b0.y, b0.z, b0.w, b1.x, b1.y, b1.z, b1.w};
#pragma unroll
            for (int i = 0; i < 8; ++i)
#pragma unroll
                for (int j = 0; j < 8; ++j)
                    acc[i][j] += a[i] * b[j];
        }
        __syncthreads();
    }

#pragma unroll
    for (int ih = 0; ih < 2; ++ih) {
#pragma unroll
        for (int i = 0; i < 4; ++i) {
            int m = m0 + ih * 64 + ty * 4 + i;
            if (m >= M) continue;
#pragma unroll
            for (int jh = 0; jh < 2; ++jh) {
                int n = n0 + jh * 64 + tx * 4;
                float4 o;
                o.x = acc[ih * 4 + i][jh * 4 + 0];
                o.y = acc[ih * 4 + i][jh * 4 + 1];
                o.z = acc[ih * 4 + i][jh * 4 + 2];
                o.w = acc[ih * 4 + i][jh * 4 + 3];
                *(float4*)(C + (size_t)m * N + n) = o;
            }
        }
    }
}

// ---------------------------------------------------------------------------
// Attention: thread-per-query; writes output as bf16 hi/lo split (feeds o-proj)
// ---------------------------------------------------------------------------
__global__ __launch_bounds__(256) void attn_kernel(
    const float* __restrict__ q, const float* __restrict__ k,
    const float* __restrict__ v,
    unsigned short* __restrict__ ohi, unsigned short* __restrict__ olo) {
    const int tid = threadIdx.x;
    const int chunk = blockIdx.x & 3;
    const int bh = blockIdx.x >> 2;
    const int h = bh % NH;
    const int b = bh / NH;
    const int s = chunk * 256 + tid;
    const float scale = 0.07905694150420949f;  // 1/sqrt(160)

    const float* qrow  = q + ((size_t)(b * SQ + s)) * CC + h * DH;
    const float* kbase = k + ((size_t)b * SENC) * CC + h * DH;
    const float* vbase = v + ((size_t)b * SENC) * CC + h * DH;

    float p[SENC];
#pragma unroll
    for (int j = 0; j < SENC; ++j) p[j] = 0.f;

    for (int d4 = 0; d4 < DH; d4 += 4) {
        float4 qv = *(const float4*)(qrow + d4);
#pragma unroll
        for (int j = 0; j < SENC; ++j) {
            float4 kv = *(const float4*)(kbase + (size_t)j * CC + d4);
            p[j] += qv.x * kv.x + qv.y * kv.y + qv.z * kv.z + qv.w * kv.w;
        }
    }

    float mx = -1e30f;
#pragma unroll
    for (int j = 0; j < SENC; ++j) { p[j] *= scale; mx = fmaxf(mx, p[j]); }
    float sum = 0.f;
#pragma unroll
    for (int j = 0; j < SENC; ++j) { p[j] = __expf(p[j] - mx); sum += p[j]; }
    float inv = 1.f / sum;
#pragma unroll
    for (int j = 0; j < SENC; ++j) p[j] *= inv;

    size_t obase = ((size_t)(b * SQ + s)) * CC + h * DH;
    for (int d4 = 0; d4 < DH; d4 += 4) {
        float4 acc = make_float4(0.f, 0.f, 0.f, 0.f);
#pragma unroll
        for (int j = 0; j < SENC; ++j) {
            float4 vv = *(const float4*)(vbase + (size_t)j * CC + d4);
            acc.x += p[j] * vv.x; acc.y += p[j] * vv.y;
            acc.z += p[j] * vv.z; acc.w += p[j] * vv.w;
        }
        unsigned short h0, h1, h2, h3, l0, l1, l2, l3;
        split_bf16(acc.x, h0, l0); split_bf16(acc.y, h1, l1);
        split_bf16(acc.z, h2, l2); split_bf16(acc.w, h3, l3);
        int2 hv, lv;
        hv.x = (int)((unsigned)h0 | ((unsigned)h1 << 16));
        hv.y = (int)((unsigned)h2 | ((unsigned)h3 << 16));
        lv.x = (int)((unsigned)l0 | ((unsigned)l1 << 16));
        lv.y = (int)((unsigned)l2 | ((unsigned)l3 << 16));
        *(int2*)(ohi + obase + d4) = hv;
        *(int2*)(olo + obase + d4) = lv;
    }
}

// ---------------------------------------------------------------------------
// Workspace layout (bytes), total = 120,094,720 (== previously-proven size):
//   Wq_hi 3,276,800 | Wq_lo | Wo_hi | Wo_lo          (13,107,200)
//   Wk_eff 5,242,880 | Wv_eff 5,242,880             (10,485,760)
//   hid_hi 41,943,040 | hid_lo 41,943,040           (83,886,080)  <- reused as att_hi/att_lo
//   k_ws 6,307,840 | v_ws 6,307,840                 (12,615,680)
// q (fp32) lives in d_out between q-gemm and attention.
// ---------------------------------------------------------------------------
extern "C" void kernel_launch(void* const* d_in, const int* in_sizes, int n_in,
                              void* d_out, int out_size, void* d_ws, size_t ws_size,
                              hipStream_t stream) {
    const float* hidden = (const float*)d_in[0];
    const float* enc    = (const float*)d_in[1];
    const float* Wq     = (const float*)d_in[2];
    const float* Wk     = (const float*)d_in[3];
    const float* Wv     = (const float*)d_in[4];
    const float* Wo     = (const float*)d_in[5];
    const float* bo     = (const float*)d_in[6];
    const float* q_down = (const float*)d_in[7];
    const float* q_up   = (const float*)d_in[8];
    const float* k_down = (const float*)d_in[9];
    const float* k_up   = (const float*)d_in[10];
    const float* v_down = (const float*)d_in[11];
    const float* v_up   = (const float*)d_in[12];
    const float* o_down = (const float*)d_in[13];
    const float* o_up   = (const float*)d_in[14];

    char* ws = (char*)d_ws;
    unsigned short* Wq_hi  = (unsigned short*)(ws);
    unsigned short* Wq_lo  = (unsigned short*)(ws + 3276800);
    unsigned short* Wo_hi  = (unsigned short*)(ws + 6553600);
    unsigned short* Wo_lo  = (unsigned short*)(ws + 9830400);
    float*          Wk_eff = (float*)(ws + 13107200);
    float*          Wv_eff = (float*)(ws + 18350080);
    unsigned short* hid_hi = (unsigned short*)(ws + 23592960);
    unsigned short* hid_lo = (unsigned short*)(ws + 65536000);
    float*          k_ws   = (float*)(ws + 107479040);
    float*          v_ws   = (float*)(ws + 113786880);
    // att splits reuse hid splits (hidden dead after q-gemm)
    unsigned short* att_hi = hid_hi;
    unsigned short* att_lo = hid_lo;
    float*          q_ws   = (float*)d_out;

    const int M1 = BB * SQ;    // 16384
    const int M2 = BB * SENC;  // 1232

    dim3 blk(256);
    // folds + splits
    fold_split_kernel<<<1600, blk, 0, stream>>>(Wq, q_up, q_down, Wq_hi, Wq_lo, CC, CC);
    fold_split_kernel<<<1600, blk, 0, stream>>>(Wo, o_up, o_down, Wo_hi, Wo_lo, CC, CC);
    fold_kernel<<<1280, blk, 0, stream>>>(Wk, k_up, k_down, Wk_eff, CC, CENC);
    fold_kernel<<<1280, blk, 0, stream>>>(Wv, v_up, v_down, Wv_eff, CC, CENC);
    split_kernel<<<20480, blk, 0, stream>>>(hidden, hid_hi, hid_lo, (M1 * CC) / 4);

    // q = hidden @ Wq_eff^T   (MFMA split-bf16) -> d_out
    gemm_bf16x3_kernel<<<dim3(CC / GBN, M1 / GBM), blk, 0, stream>>>(
        hid_hi, hid_lo, Wq_hi, Wq_lo, nullptr, q_ws, M1, CC, CC);

    // k/v = enc @ W{k,v}_eff^T  (fp32 vector path, small)
    gemm_nt_kernel<<<dim3(CC / BN, (M2 + BM - 1) / BM), blk, 0, stream>>>(
        enc, Wk_eff, nullptr, k_ws, M2, CC, CENC);
    gemm_nt_kernel<<<dim3(CC / BN, (M2 + BM - 1) / BM), blk, 0, stream>>>(
        enc, Wv_eff, nullptr, v_ws, M2, CC, CENC);

    // attention: q(d_out) x k,v -> att splits (over hid splits)
    attn_kernel<<<BB * NH * 4, blk, 0, stream>>>(q_ws, k_ws, v_ws, att_hi, att_lo);

    // out = att @ Wo_eff^T + bo  (MFMA split-bf16) -> d_out
    gemm_bf16x3_kernel<<<dim3(CC / GBN, M1 / GBM), blk, 0, stream>>>(
        att_hi, att_lo, Wo_hi, Wo_lo, bo, (float*)d_out, M1, CC, CC);
}

// Round 3
// 1095.792 us; speedup vs baseline: 1.8299x; 1.1750x over previous
//
#include <hip/hip_runtime.h>

// Problem constants
#define NH    8
#define BB    16
#define SQ    1024
#define CC    1280
#define SENC  77
#define CENC  1024
#define DH    160
#define RANK  4

typedef __attribute__((ext_vector_type(8))) short bf16x8;
typedef __attribute__((ext_vector_type(4))) float f32x4;

// ---------------------------------------------------------------------------
// fp32 -> bf16 hi/lo split (truncation; hi+lo captures ~16 mantissa bits)
// ---------------------------------------------------------------------------
__device__ inline void split_bf16(float a, unsigned short& hi, unsigned short& lo) {
    unsigned u = __float_as_uint(a);
    hi = (unsigned short)(u >> 16);
    float fhi = __uint_as_float(u & 0xffff0000u);
    float r = a - fhi;
    lo = (unsigned short)(__float_as_uint(r) >> 16);
}

// ---------------------------------------------------------------------------
// Weight fold + bf16 hi/lo split: Weff = W + up@down
// ---------------------------------------------------------------------------
__global__ void fold_split_kernel(const float* __restrict__ W,
                                  const float* __restrict__ up,
                                  const float* __restrict__ down,
                                  unsigned short* __restrict__ ohi,
                                  unsigned short* __restrict__ olo,
                                  int N, int K) {
    int idx4 = blockIdx.x * blockDim.x + threadIdx.x;
    int total4 = (N * K) >> 2;
    if (idx4 >= total4) return;
    int i = idx4 << 2;
    int n = i / K;
    int kk = i - n * K;
    float4 acc = *(const float4*)(W + i);
#pragma unroll
    for (int r = 0; r < RANK; ++r) {
        float u = up[n * RANK + r];
        float4 dv = *(const float4*)(down + (size_t)r * K + kk);
        acc.x += u * dv.x; acc.y += u * dv.y;
        acc.z += u * dv.z; acc.w += u * dv.w;
    }
    unsigned short h0, h1, h2, h3, l0, l1, l2, l3;
    split_bf16(acc.x, h0, l0); split_bf16(acc.y, h1, l1);
    split_bf16(acc.z, h2, l2); split_bf16(acc.w, h3, l3);
    int2 hv, lv;
    hv.x = (int)((unsigned)h0 | ((unsigned)h1 << 16));
    hv.y = (int)((unsigned)h2 | ((unsigned)h3 << 16));
    lv.x = (int)((unsigned)l0 | ((unsigned)l1 << 16));
    lv.y = (int)((unsigned)l2 | ((unsigned)l3 << 16));
    *(int2*)(ohi + i) = hv;
    *(int2*)(olo + i) = lv;
}

// ---------------------------------------------------------------------------
// Activation fp32 -> bf16 hi/lo split
// ---------------------------------------------------------------------------
__global__ void split_kernel(const float* __restrict__ x,
                             unsigned short* __restrict__ ohi,
                             unsigned short* __restrict__ olo, int total4) {
    int idx4 = blockIdx.x * blockDim.x + threadIdx.x;
    if (idx4 >= total4) return;
    int i = idx4 << 2;
    float4 a = *(const float4*)(x + i);
    unsigned short h0, h1, h2, h3, l0, l1, l2, l3;
    split_bf16(a.x, h0, l0); split_bf16(a.y, h1, l1);
    split_bf16(a.z, h2, l2); split_bf16(a.w, h3, l3);
    int2 hv, lv;
    hv.x = (int)((unsigned)h0 | ((unsigned)h1 << 16));
    hv.y = (int)((unsigned)h2 | ((unsigned)h3 << 16));
    lv.x = (int)((unsigned)l0 | ((unsigned)l1 << 16));
    lv.y = (int)((unsigned)l2 | ((unsigned)l3 << 16));
    *(int2*)(ohi + i) = hv;
    *(int2*)(olo + i) = lv;
}

// ---------------------------------------------------------------------------
// MFMA split-bf16 GEMM: C[m][n] = sum_k A[m][k]*W[n][k] (+bias[n]), fp32-accurate
// via A_hi*W_hi + A_hi*W_lo + A_lo*W_hi. 128x128 tile, BK=32, 4 waves.
// N%128==0, K%32==0 required; M guarded (staging rows clamped, stores masked).
// ---------------------------------------------------------------------------
#define GBM 128
#define GBN 128
#define GBK 32

__device__ inline void async_load16(const void* gsrc, void* lds_dst) {
    __builtin_amdgcn_global_load_lds(
        (const __attribute__((address_space(1))) void*)gsrc,
        (__attribute__((address_space(3))) void*)lds_dst, 16, 0, 0);
}

__device__ inline int clampi(int x, int hi) { return x > hi ? hi : x; }

__global__ __launch_bounds__(256) void gemm_bf16x3_kernel(
    const unsigned short* __restrict__ A_hi, const unsigned short* __restrict__ A_lo,
    const unsigned short* __restrict__ W_hi, const unsigned short* __restrict__ W_lo,
    const float* __restrict__ bias, float* __restrict__ C,
    int M, int N, int K) {
    __shared__ __align__(16) unsigned short lds[4][GBM][GBK];
    const int tid  = threadIdx.x;
    const int wave = tid >> 6;
    const int lane = tid & 63;
    const int m0 = blockIdx.y * GBM;
    const int n0 = blockIdx.x * GBN;
    const int wr = wave >> 1, wc = wave & 1;

    f32x4 zero = {0.f, 0.f, 0.f, 0.f};
    f32x4 acc[4][4];
#pragma unroll
    for (int i = 0; i < 4; ++i)
#pragma unroll
        for (int j = 0; j < 4; ++j) acc[i][j] = zero;

    const int c0 = wave * 2, c1 = wave * 2 + 1;
    const int rr = lane >> 2;
    const int kc = (lane & 3) * 8;
    const int ra0 = clampi(m0 + c0 * 16 + rr, M - 1);   // row clamp for ragged M
    const int ra1 = clampi(m0 + c1 * 16 + rr, M - 1);
    const unsigned short* pAh0 = A_hi + (size_t)ra0 * K + kc;
    const unsigned short* pAh1 = A_hi + (size_t)ra1 * K + kc;
    const unsigned short* pAl0 = A_lo + (size_t)ra0 * K + kc;
    const unsigned short* pAl1 = A_lo + (size_t)ra1 * K + kc;
    const unsigned short* pWh0 = W_hi + (size_t)(n0 + c0 * 16 + rr) * K + kc;
    const unsigned short* pWh1 = W_hi + (size_t)(n0 + c1 * 16 + rr) * K + kc;
    const unsigned short* pWl0 = W_lo + (size_t)(n0 + c0 * 16 + rr) * K + kc;
    const unsigned short* pWl1 = W_lo + (size_t)(n0 + c1 * 16 + rr) * K + kc;

    for (int k0 = 0; k0 < K; k0 += GBK) {
        async_load16(pAh0 + k0, &lds[0][c0 * 16][0]);
        async_load16(pAh1 + k0, &lds[0][c1 * 16][0]);
        async_load16(pAl0 + k0, &lds[1][c0 * 16][0]);
        async_load16(pAl1 + k0, &lds[1][c1 * 16][0]);
        async_load16(pWh0 + k0, &lds[2][c0 * 16][0]);
        async_load16(pWh1 + k0, &lds[2][c1 * 16][0]);
        async_load16(pWl0 + k0, &lds[3][c0 * 16][0]);
        async_load16(pWl1 + k0, &lds[3][c1 * 16][0]);
        __syncthreads();

        bf16x8 ah[4], al[4], bh[4], bl[4];
        const int fr = lane & 15;
        const int kb = (lane >> 4) * 8;
#pragma unroll
        for (int i = 0; i < 4; ++i) {
            ah[i] = *(const bf16x8*)&lds[0][wr * 64 + i * 16 + fr][kb];
            al[i] = *(const bf16x8*)&lds[1][wr * 64 + i * 16 + fr][kb];
            bh[i] = *(const bf16x8*)&lds[2][wc * 64 + i * 16 + fr][kb];
            bl[i] = *(const bf16x8*)&lds[3][wc * 64 + i * 16 + fr][kb];
        }
#pragma unroll
        for (int i = 0; i < 4; ++i)
#pragma unroll
            for (int j = 0; j < 4; ++j) {
                acc[i][j] = __builtin_amdgcn_mfma_f32_16x16x32_bf16(ah[i], bh[j], acc[i][j], 0, 0, 0);
                acc[i][j] = __builtin_amdgcn_mfma_f32_16x16x32_bf16(ah[i], bl[j], acc[i][j], 0, 0, 0);
                acc[i][j] = __builtin_amdgcn_mfma_f32_16x16x32_bf16(al[i], bh[j], acc[i][j], 0, 0, 0);
            }
        __syncthreads();
    }

    // C/D layout: col=lane&15, row=(lane>>4)*4+reg  [m89-verified]
    const int fc = lane & 15;
    const int fr4 = (lane >> 4) * 4;
#pragma unroll
    for (int j = 0; j < 4; ++j) {
        int col = n0 + wc * 64 + j * 16 + fc;
        float bv = bias ? bias[col] : 0.f;
#pragma unroll
        for (int i = 0; i < 4; ++i) {
            int row = m0 + wr * 64 + i * 16 + fr4;
#pragma unroll
            for (int r = 0; r < 4; ++r)
                if (row + r < M)
                    C[(size_t)(row + r) * N + col] = acc[i][j][r] + bv;
        }
    }
}

// ---------------------------------------------------------------------------
// Cooperative attention: block = (b, h, 64 queries), 256 threads, 4 waves.
// Phase A: thread (q=tid&63, jg=tid>>6) computes scores for ~20 keys; partial
//   max/sum reduced via LDS; exp'd scores parked in sc[64][81] (pad->no conflict).
// Phase B: lane=(qsub,d4i): 16 consecutive lanes cover 256B of one output row
//   -> coalesced bf16 hi/lo writes. V read as wave-broadcast 256B lines.
// kv layout: [B*SENC][2*CC], k at cols [h*DH..], v at cols [CC+h*DH..].
// ---------------------------------------------------------------------------
#define QBLK 64
#define KVSTR (2 * CC)

__global__ __launch_bounds__(256) void attn_kernel(
    const float* __restrict__ q, const float* __restrict__ kv,
    unsigned short* __restrict__ ohi, unsigned short* __restrict__ olo) {
    __shared__ float sc[QBLK][81];
    __shared__ float pm[4][QBLK];
    __shared__ float ps[4][QBLK];

    const int tid = threadIdx.x;
    const int chunk = blockIdx.x & 15;
    const int bh = blockIdx.x >> 4;
    const int h = bh & 7;
    const int b = bh >> 3;
    const int s0 = chunk * QBLK;
    const float scale = 0.07905694150420949f;  // 1/sqrt(160)

    const float* kbase = kv + (size_t)(b * SENC) * KVSTR + h * DH;
    const float* vbase = kbase + CC;

    // ---- Phase A: scores ----
    {
        const int qa = tid & 63;
        const int jg = tid >> 6;
        const int jstart = jg * 20;
        const int jcount = (SENC - jstart < 20) ? (SENC - jstart) : 20;  // 20,20,20,17
        const float* qrow = q + (size_t)(b * SQ + s0 + qa) * CC + h * DH;

        float pp[20];
#pragma unroll
        for (int jj = 0; jj < 20; ++jj) pp[jj] = 0.f;

        for (int d4 = 0; d4 < DH / 4; ++d4) {
            float4 qv = *(const float4*)(qrow + d4 * 4);
#pragma unroll
            for (int jj = 0; jj < 20; ++jj) {
                if (jj < jcount) {
                    float4 kx = *(const float4*)(kbase + (size_t)(jstart + jj) * KVSTR + d4 * 4);
                    pp[jj] += qv.x * kx.x + qv.y * kx.y + qv.z * kx.z + qv.w * kx.w;
                }
            }
        }
        float mx = -1e30f;
#pragma unroll
        for (int jj = 0; jj < 20; ++jj)
            if (jj < jcount) { pp[jj] *= scale; mx = fmaxf(mx, pp[jj]); }
        pm[jg][qa] = mx;
        __syncthreads();
        mx = fmaxf(fmaxf(pm[0][qa], pm[1][qa]), fmaxf(pm[2][qa], pm[3][qa]));
        float sum = 0.f;
#pragma unroll
        for (int jj = 0; jj < 20; ++jj)
            if (jj < jcount) {
                float e = __expf(pp[jj] - mx);
                sum += e;
                sc[qa][jstart + jj] = e;
            }
        ps[jg][qa] = sum;
        __syncthreads();
    }

    // ---- Phase B: PV + coalesced split-bf16 write ----
    {
        const int wave = tid >> 6;
        const int lane = tid & 63;
        const int qsub = lane >> 4;   // 0..3
        const int d4i = lane & 15;    // 0..15
        const int qb = wave * 16;

        float inv[4];
#pragma unroll
        for (int qi = 0; qi < 4; ++qi) {
            int ql = qb + qi * 4 + qsub;
            inv[qi] = 1.f / (ps[0][ql] + ps[1][ql] + ps[2][ql] + ps[3][ql]);
        }

        for (int dblock = 0; dblock < 3; ++dblock) {
            int d4 = dblock * 16 + d4i;
            bool active = d4 < DH / 4;
            int d4c = active ? d4 : (DH / 4 - 1);

            float4 a0 = make_float4(0.f, 0.f, 0.f, 0.f);
            float4 a1 = a0, a2 = a0, a3 = a0;
            for (int j = 0; j < SENC; ++j) {
                float4 v4 = *(const float4*)(vbase + (size_t)j * KVSTR + d4c * 4);
                float p0 = sc[qb + 0 * 4 + qsub][j];
                float p1 = sc[qb + 1 * 4 + qsub][j];
                float p2 = sc[qb + 2 * 4 + qsub][j];
                float p3 = sc[qb + 3 * 4 + qsub][j];
                a0.x += p0 * v4.x; a0.y += p0 * v4.y; a0.z += p0 * v4.z; a0.w += p0 * v4.w;
                a1.x += p1 * v4.x; a1.y += p1 * v4.y; a1.z += p1 * v4.z; a1.w += p1 * v4.w;
                a2.x += p2 * v4.x; a2.y += p2 * v4.y; a2.z += p2 * v4.z; a2.w += p2 * v4.w;
                a3.x += p3 * v4.x; a3.y += p3 * v4.y; a3.z += p3 * v4.z; a3.w += p3 * v4.w;
            }
            if (active) {
                float4 acc[4] = {a0, a1, a2, a3};
#pragma unroll
                for (int qi = 0; qi < 4; ++qi) {
                    int ql = qb + qi * 4 + qsub;
                    size_t ob = (size_t)(b * SQ + s0 + ql) * CC + h * DH + d4 * 4;
                    float4 r;
                    r.x = acc[qi].x * inv[qi]; r.y = acc[qi].y * inv[qi];
                    r.z = acc[qi].z * inv[qi]; r.w = acc[qi].w * inv[qi];
                    unsigned short h0, h1, h2, h3, l0, l1, l2, l3;
                    split_bf16(r.x, h0, l0); split_bf16(r.y, h1, l1);
                    split_bf16(r.z, h2, l2); split_bf16(r.w, h3, l3);
                    int2 hv, lv;
                    hv.x = (int)((unsigned)h0 | ((unsigned)h1 << 16));
                    hv.y = (int)((unsigned)h2 | ((unsigned)h3 << 16));
                    lv.x = (int)((unsigned)l0 | ((unsigned)l1 << 16));
                    lv.y = (int)((unsigned)l2 | ((unsigned)l3 << 16));
                    *(int2*)(ohi + ob) = hv;
                    *(int2*)(olo + ob) = lv;
                }
            }
        }
    }
}

// ---------------------------------------------------------------------------
// Workspace layout (bytes), total = 120,094,720:
//   Wq_hi/lo 6,553,600 | Wo_hi/lo 6,553,600 | Wkv_hi/lo 10,485,760
//   hid region 83,886,080 (hid splits -> enc splits overlay -> att splits)
//   kv_ws 12,615,680
// q (fp32) lives in d_out between q-gemm and attention.
// ---------------------------------------------------------------------------
extern "C" void kernel_launch(void* const* d_in, const int* in_sizes, int n_in,
                              void* d_out, int out_size, void* d_ws, size_t ws_size,
                              hipStream_t stream) {
    const float* hidden = (const float*)d_in[0];
    const float* enc    = (const float*)d_in[1];
    const float* Wq     = (const float*)d_in[2];
    const float* Wk     = (const float*)d_in[3];
    const float* Wv     = (const float*)d_in[4];
    const float* Wo     = (const float*)d_in[5];
    const float* bo     = (const float*)d_in[6];
    const float* q_down = (const float*)d_in[7];
    const float* q_up   = (const float*)d_in[8];
    const float* k_down = (const float*)d_in[9];
    const float* k_up   = (const float*)d_in[10];
    const float* v_down = (const float*)d_in[11];
    const float* v_up   = (const float*)d_in[12];
    const float* o_down = (const float*)d_in[13];
    const float* o_up   = (const float*)d_in[14];

    char* ws = (char*)d_ws;
    unsigned short* Wq_hi  = (unsigned short*)(ws);
    unsigned short* Wq_lo  = (unsigned short*)(ws + 3276800);
    unsigned short* Wo_hi  = (unsigned short*)(ws + 6553600);
    unsigned short* Wo_lo  = (unsigned short*)(ws + 9830400);
    unsigned short* Wkv_hi = (unsigned short*)(ws + 13107200);  // [2560][1024]
    unsigned short* Wkv_lo = (unsigned short*)(ws + 18350080);
    unsigned short* hid_hi = (unsigned short*)(ws + 23592960);
    unsigned short* hid_lo = (unsigned short*)(ws + 65536000);
    float*          kv_ws  = (float*)(ws + 107479040);          // [1232][2560]
    // enc splits overlay the (dead-after-q-gemm) hid region
    unsigned short* enc_hi = hid_hi;
    unsigned short* enc_lo = (unsigned short*)(ws + 23592960 + 2523136);
    unsigned short* att_hi = hid_hi;
    unsigned short* att_lo = hid_lo;
    float*          q_ws   = (float*)d_out;

    const int M1 = BB * SQ;    // 16384
    const int M2 = BB * SENC;  // 1232

    dim3 blk(256);
    // weight folds + splits
    fold_split_kernel<<<1600, blk, 0, stream>>>(Wq, q_up, q_down, Wq_hi, Wq_lo, CC, CC);
    fold_split_kernel<<<1600, blk, 0, stream>>>(Wo, o_up, o_down, Wo_hi, Wo_lo, CC, CC);
    fold_split_kernel<<<1280, blk, 0, stream>>>(Wk, k_up, k_down, Wkv_hi, Wkv_lo, CC, CENC);
    fold_split_kernel<<<1280, blk, 0, stream>>>(Wv, v_up, v_down,
                                                Wkv_hi + 1310720, Wkv_lo + 1310720, CC, CENC);
    split_kernel<<<20480, blk, 0, stream>>>(hidden, hid_hi, hid_lo, (M1 * CC) / 4);

    // q = hidden @ Wq_eff^T -> d_out (fp32)
    gemm_bf16x3_kernel<<<dim3(CC / GBN, M1 / GBM), blk, 0, stream>>>(
        hid_hi, hid_lo, Wq_hi, Wq_lo, nullptr, q_ws, M1, CC, CC);

    // enc split (overlays dead hid region), then fused k|v projection
    split_kernel<<<1232, blk, 0, stream>>>(enc, enc_hi, enc_lo, (M2 * CENC) / 4);
    gemm_bf16x3_kernel<<<dim3((2 * CC) / GBN, (M2 + GBM - 1) / GBM), blk, 0, stream>>>(
        enc_hi, enc_lo, Wkv_hi, Wkv_lo, nullptr, kv_ws, M2, 2 * CC, CENC);

    // attention: q(d_out) x kv -> att splits (overwrites enc splits, now dead)
    attn_kernel<<<BB * NH * 16, blk, 0, stream>>>(q_ws, kv_ws, att_hi, att_lo);

    // out = att @ Wo_eff^T + bo -> d_out
    gemm_bf16x3_kernel<<<dim3(CC / GBN, M1 / GBM), blk, 0, stream>>>(
        att_hi, att_lo, Wo_hi, Wo_lo, bo, (float*)d_out, M1, CC, CC);
}

// Round 4
// 764.135 us; speedup vs baseline: 2.6242x; 1.4340x over previous
//
#include <hip/hip_runtime.h>

// Problem constants
#define NH    8
#define BB    16
#define SQ    1024
#define CC    1280
#define SENC  77
#define CENC  1024
#define DH    160
#define RANK  4

typedef __attribute__((ext_vector_type(8))) short bf16x8;
typedef __attribute__((ext_vector_type(4))) float f32x4;

// ---------------------------------------------------------------------------
// fp32 -> bf16 hi/lo split (truncation; hi+lo captures ~16 mantissa bits)
// ---------------------------------------------------------------------------
__device__ inline void split_bf16(float a, unsigned short& hi, unsigned short& lo) {
    unsigned u = __float_as_uint(a);
    hi = (unsigned short)(u >> 16);
    float fhi = __uint_as_float(u & 0xffff0000u);
    float r = a - fhi;
    lo = (unsigned short)(__float_as_uint(r) >> 16);
}

// ---------------------------------------------------------------------------
// Weight fold + bf16 hi/lo split: Weff = W + up@down
// ---------------------------------------------------------------------------
__global__ void fold_split_kernel(const float* __restrict__ W,
                                  const float* __restrict__ up,
                                  const float* __restrict__ down,
                                  unsigned short* __restrict__ ohi,
                                  unsigned short* __restrict__ olo,
                                  int N, int K) {
    int idx4 = blockIdx.x * blockDim.x + threadIdx.x;
    int total4 = (N * K) >> 2;
    if (idx4 >= total4) return;
    int i = idx4 << 2;
    int n = i / K;
    int kk = i - n * K;
    float4 acc = *(const float4*)(W + i);
#pragma unroll
    for (int r = 0; r < RANK; ++r) {
        float u = up[n * RANK + r];
        float4 dv = *(const float4*)(down + (size_t)r * K + kk);
        acc.x += u * dv.x; acc.y += u * dv.y;
        acc.z += u * dv.z; acc.w += u * dv.w;
    }
    unsigned short h0, h1, h2, h3, l0, l1, l2, l3;
    split_bf16(acc.x, h0, l0); split_bf16(acc.y, h1, l1);
    split_bf16(acc.z, h2, l2); split_bf16(acc.w, h3, l3);
    int2 hv, lv;
    hv.x = (int)((unsigned)h0 | ((unsigned)h1 << 16));
    hv.y = (int)((unsigned)h2 | ((unsigned)h3 << 16));
    lv.x = (int)((unsigned)l0 | ((unsigned)l1 << 16));
    lv.y = (int)((unsigned)l2 | ((unsigned)l3 << 16));
    *(int2*)(ohi + i) = hv;
    *(int2*)(olo + i) = lv;
}

// ---------------------------------------------------------------------------
// Activation fp32 -> bf16 hi/lo split
// ---------------------------------------------------------------------------
__global__ void split_kernel(const float* __restrict__ x,
                             unsigned short* __restrict__ ohi,
                             unsigned short* __restrict__ olo, int total4) {
    int idx4 = blockIdx.x * blockDim.x + threadIdx.x;
    if (idx4 >= total4) return;
    int i = idx4 << 2;
    float4 a = *(const float4*)(x + i);
    unsigned short h0, h1, h2, h3, l0, l1, l2, l3;
    split_bf16(a.x, h0, l0); split_bf16(a.y, h1, l1);
    split_bf16(a.z, h2, l2); split_bf16(a.w, h3, l3);
    int2 hv, lv;
    hv.x = (int)((unsigned)h0 | ((unsigned)h1 << 16));
    hv.y = (int)((unsigned)h2 | ((unsigned)h3 << 16));
    lv.x = (int)((unsigned)l0 | ((unsigned)l1 << 16));
    lv.y = (int)((unsigned)l2 | ((unsigned)l3 << 16));
    *(int2*)(ohi + i) = hv;
    *(int2*)(olo + i) = lv;
}

// ---------------------------------------------------------------------------
// MFMA split-bf16 GEMM, templated epilogue:
//   MODE 0: Cf[row][col] = val (+bias)
//   MODE 1: split-bf16 -> out_hi/out_lo [row][col]  (row-major, N stride)
//   MODE 2: split-bf16 transposed per-batch: b=row/77, j=row%77,
//           out[(b*1280+col)*96 + j]   (Vt layout for attention PV)
// ---------------------------------------------------------------------------
#define GBM 128
#define GBN 128
#define GBK 32

__device__ inline void async_load16(const void* gsrc, void* lds_dst) {
    __builtin_amdgcn_global_load_lds(
        (const __attribute__((address_space(1))) void*)gsrc,
        (__attribute__((address_space(3))) void*)lds_dst, 16, 0, 0);
}

__device__ inline int clampi(int x, int hi) { return x > hi ? hi : x; }

template <int MODE>
__global__ __launch_bounds__(256) void gemm_bf16x3_kernel(
    const unsigned short* __restrict__ A_hi, const unsigned short* __restrict__ A_lo,
    const unsigned short* __restrict__ W_hi, const unsigned short* __restrict__ W_lo,
    const float* __restrict__ bias, float* __restrict__ Cf,
    unsigned short* __restrict__ out_hi, unsigned short* __restrict__ out_lo,
    int M, int N, int K) {
    __shared__ __align__(16) unsigned short lds[4][GBM][GBK];
    const int tid  = threadIdx.x;
    const int wave = tid >> 6;
    const int lane = tid & 63;
    const int m0 = blockIdx.y * GBM;
    const int n0 = blockIdx.x * GBN;
    const int wr = wave >> 1, wc = wave & 1;

    f32x4 zero = {0.f, 0.f, 0.f, 0.f};
    f32x4 acc[4][4];
#pragma unroll
    for (int i = 0; i < 4; ++i)
#pragma unroll
        for (int j = 0; j < 4; ++j) acc[i][j] = zero;

    const int c0 = wave * 2, c1 = wave * 2 + 1;
    const int rr = lane >> 2;
    const int kc = (lane & 3) * 8;
    const int ra0 = clampi(m0 + c0 * 16 + rr, M - 1);
    const int ra1 = clampi(m0 + c1 * 16 + rr, M - 1);
    const unsigned short* pAh0 = A_hi + (size_t)ra0 * K + kc;
    const unsigned short* pAh1 = A_hi + (size_t)ra1 * K + kc;
    const unsigned short* pAl0 = A_lo + (size_t)ra0 * K + kc;
    const unsigned short* pAl1 = A_lo + (size_t)ra1 * K + kc;
    const unsigned short* pWh0 = W_hi + (size_t)(n0 + c0 * 16 + rr) * K + kc;
    const unsigned short* pWh1 = W_hi + (size_t)(n0 + c1 * 16 + rr) * K + kc;
    const unsigned short* pWl0 = W_lo + (size_t)(n0 + c0 * 16 + rr) * K + kc;
    const unsigned short* pWl1 = W_lo + (size_t)(n0 + c1 * 16 + rr) * K + kc;

    for (int k0 = 0; k0 < K; k0 += GBK) {
        async_load16(pAh0 + k0, &lds[0][c0 * 16][0]);
        async_load16(pAh1 + k0, &lds[0][c1 * 16][0]);
        async_load16(pAl0 + k0, &lds[1][c0 * 16][0]);
        async_load16(pAl1 + k0, &lds[1][c1 * 16][0]);
        async_load16(pWh0 + k0, &lds[2][c0 * 16][0]);
        async_load16(pWh1 + k0, &lds[2][c1 * 16][0]);
        async_load16(pWl0 + k0, &lds[3][c0 * 16][0]);
        async_load16(pWl1 + k0, &lds[3][c1 * 16][0]);
        __syncthreads();

        bf16x8 ah[4], al[4], bh[4], bl[4];
        const int fr = lane & 15;
        const int kb = (lane >> 4) * 8;
#pragma unroll
        for (int i = 0; i < 4; ++i) {
            ah[i] = *(const bf16x8*)&lds[0][wr * 64 + i * 16 + fr][kb];
            al[i] = *(const bf16x8*)&lds[1][wr * 64 + i * 16 + fr][kb];
            bh[i] = *(const bf16x8*)&lds[2][wc * 64 + i * 16 + fr][kb];
            bl[i] = *(const bf16x8*)&lds[3][wc * 64 + i * 16 + fr][kb];
        }
#pragma unroll
        for (int i = 0; i < 4; ++i)
#pragma unroll
            for (int j = 0; j < 4; ++j) {
                acc[i][j] = __builtin_amdgcn_mfma_f32_16x16x32_bf16(ah[i], bh[j], acc[i][j], 0, 0, 0);
                acc[i][j] = __builtin_amdgcn_mfma_f32_16x16x32_bf16(ah[i], bl[j], acc[i][j], 0, 0, 0);
                acc[i][j] = __builtin_amdgcn_mfma_f32_16x16x32_bf16(al[i], bh[j], acc[i][j], 0, 0, 0);
            }
        __syncthreads();
    }

    // C/D layout: col=lane&15, row=(lane>>4)*4+reg  [m89-verified]
    const int fc = lane & 15;
    const int fr4 = (lane >> 4) * 4;
#pragma unroll
    for (int j = 0; j < 4; ++j) {
        int col = n0 + wc * 64 + j * 16 + fc;
        float bv = (MODE == 0 && bias) ? bias[col] : 0.f;
#pragma unroll
        for (int i = 0; i < 4; ++i) {
            int row = m0 + wr * 64 + i * 16 + fr4;
#pragma unroll
            for (int r = 0; r < 4; ++r) {
                if (row + r >= M) continue;
                float val = acc[i][j][r] + bv;
                if (MODE == 0) {
                    Cf[(size_t)(row + r) * N + col] = val;
                } else if (MODE == 1) {
                    unsigned short vh, vl;
                    split_bf16(val, vh, vl);
                    out_hi[(size_t)(row + r) * N + col] = vh;
                    out_lo[(size_t)(row + r) * N + col] = vl;
                } else {
                    int rw = row + r;
                    int bb_ = (rw * 3405) >> 18;      // exact /77 for rw<6394
                    int jj = rw - bb_ * 77;
                    size_t idx = ((size_t)bb_ * 1280 + col) * 96 + jj;
                    unsigned short vh, vl;
                    split_bf16(val, vh, vl);
                    out_hi[idx] = vh;
                    out_lo[idx] = vl;
                }
            }
        }
    }
}

// ---------------------------------------------------------------------------
// MFMA flash attention: block = (b, h, 128 q-rows), 256 threads (4 waves),
// each wave owns 32 q-rows. Split-bf16 x3 for QK^T and PV (fp32 accuracy).
//   LDS: K hi/lo [80][168] (rows 77..79 zeroed)  -- then reused for P [128][104]
//   scores softmax in registers via 16-lane shfl_xor reductions
//   Vt B-frags read directly from global (pre-transposed split layout)
// ---------------------------------------------------------------------------
__global__ __launch_bounds__(256) void attn_mfma_kernel(
    const unsigned short* __restrict__ q_hi, const unsigned short* __restrict__ q_lo,
    const float* __restrict__ k_ws,
    const unsigned short* __restrict__ vt_hi, const unsigned short* __restrict__ vt_lo,
    unsigned short* __restrict__ att_hi, unsigned short* __restrict__ att_lo) {
    __shared__ __align__(16) unsigned short sbuf[26880];
    unsigned short* Khi = sbuf;            // [80][168]
    unsigned short* Klo = sbuf + 13440;
    unsigned short* Phi = sbuf;            // [128][104]  (after K is dead)
    unsigned short* Plo = sbuf + 13312;

    const int tid = threadIdx.x;
    const int wave = tid >> 6, lane = tid & 63;
    const int fr = lane & 15;        // frag row (A/B) == frag col (C/D)
    const int g = lane >> 4;
    const int kb = g * 8;
    const int bid = blockIdx.x;
    const int chunk = bid & 7;
    const int h = (bid >> 3) & 7;
    const int b = bid >> 6;
    const float scale = 0.07905694150420949f;  // 1/sqrt(160)

    // ---- stage K: fp32 global -> bf16 hi/lo LDS; zero rows 77..79 ----
    for (int idx = tid; idx < 3200; idx += 256) {
        int j = idx / 40;
        int c4 = idx - j * 40;
        unsigned int h01 = 0, h23 = 0, l01 = 0, l23 = 0;
        if (j < SENC) {
            float4 kv = *(const float4*)(k_ws + (size_t)(b * SENC + j) * CC + h * DH + c4 * 4);
            unsigned short a0, a1, a2, a3, b0, b1, b2, b3;
            split_bf16(kv.x, a0, b0); split_bf16(kv.y, a1, b1);
            split_bf16(kv.z, a2, b2); split_bf16(kv.w, a3, b3);
            h01 = (unsigned)a0 | ((unsigned)a1 << 16);
            h23 = (unsigned)a2 | ((unsigned)a3 << 16);
            l01 = (unsigned)b0 | ((unsigned)b1 << 16);
            l23 = (unsigned)b2 | ((unsigned)b3 << 16);
        }
        uint2 hv; hv.x = h01; hv.y = h23;
        uint2 lv; lv.x = l01; lv.y = l23;
        *(uint2*)(Khi + j * 168 + c4 * 4) = hv;
        *(uint2*)(Klo + j * 168 + c4 * 4) = lv;
    }
    __syncthreads();

    // ---- QK^T: scores tile 128x80 (5 j-frags), contraction over d=160 ----
    f32x4 zero = {0.f, 0.f, 0.f, 0.f};
    f32x4 s[2][5];
#pragma unroll
    for (int i = 0; i < 2; ++i)
#pragma unroll
        for (int jf = 0; jf < 5; ++jf) s[i][jf] = zero;

    const size_t qrow0 = (size_t)b * SQ + chunk * 128 + wave * 32;
    const unsigned short* qh_base = q_hi + qrow0 * CC + h * DH;
    const unsigned short* ql_base = q_lo + qrow0 * CC + h * DH;

#pragma unroll
    for (int ks = 0; ks < 5; ++ks) {
        bf16x8 qh[2], ql[2];
#pragma unroll
        for (int i = 0; i < 2; ++i) {
            qh[i] = *(const bf16x8*)(qh_base + (size_t)(i * 16 + fr) * CC + ks * 32 + kb);
            ql[i] = *(const bf16x8*)(ql_base + (size_t)(i * 16 + fr) * CC + ks * 32 + kb);
        }
#pragma unroll
        for (int jf = 0; jf < 5; ++jf) {
            bf16x8 bh = *(const bf16x8*)(Khi + (jf * 16 + fr) * 168 + ks * 32 + kb);
            bf16x8 bl = *(const bf16x8*)(Klo + (jf * 16 + fr) * 168 + ks * 32 + kb);
#pragma unroll
            for (int i = 0; i < 2; ++i) {
                s[i][jf] = __builtin_amdgcn_mfma_f32_16x16x32_bf16(qh[i], bh, s[i][jf], 0, 0, 0);
                s[i][jf] = __builtin_amdgcn_mfma_f32_16x16x32_bf16(qh[i], bl, s[i][jf], 0, 0, 0);
                s[i][jf] = __builtin_amdgcn_mfma_f32_16x16x32_bf16(ql[i], bh, s[i][jf], 0, 0, 0);
            }
        }
    }

    // ---- softmax in registers (rows live across the 16-lane fc group) ----
    const int fc = fr;  // C/D col = lane&15
    float inv_[2][4];
#pragma unroll
    for (int i = 0; i < 2; ++i) {
#pragma unroll
        for (int jf = 0; jf < 5; ++jf)
#pragma unroll
            for (int r = 0; r < 4; ++r) {
                float v = s[i][jf][r] * scale;
                if (jf == 4 && fc >= 13) v = -1e30f;  // mask j >= 77
                s[i][jf][r] = v;
            }
#pragma unroll
        for (int r = 0; r < 4; ++r) {
            float m = fmaxf(fmaxf(fmaxf(s[i][0][r], s[i][1][r]),
                                  fmaxf(s[i][2][r], s[i][3][r])), s[i][4][r]);
#pragma unroll
            for (int msk = 1; msk < 16; msk <<= 1) m = fmaxf(m, __shfl_xor(m, msk));
            float sum = 0.f;
#pragma unroll
            for (int jf = 0; jf < 5; ++jf) {
                float e = __expf(s[i][jf][r] - m);
                s[i][jf][r] = e;
                sum += e;
            }
#pragma unroll
            for (int msk = 1; msk < 16; msk <<= 1) sum += __shfl_xor(sum, msk);
            inv_[i][r] = 1.f / sum;
        }
    }

    __syncthreads();  // all waves done reading K LDS

    // ---- write P splits into LDS (reusing K space) ----
#pragma unroll
    for (int i = 0; i < 2; ++i)
#pragma unroll
        for (int jf = 0; jf < 5; ++jf)
#pragma unroll
            for (int r = 0; r < 4; ++r) {
                int row = wave * 32 + i * 16 + g * 4 + r;
                int col = jf * 16 + fc;
                unsigned short ph, pl;
                split_bf16(s[i][jf][r], ph, pl);
                Phi[row * 104 + col] = ph;
                Plo[row * 104 + col] = pl;
            }
    // zero P cols 80..95 (PV k-padding)
    for (int idx = tid; idx < 1024; idx += 256) {
        int row = idx >> 3, c = idx & 7;
        *(unsigned int*)(Phi + row * 104 + 80 + c * 2) = 0u;
        *(unsigned int*)(Plo + row * 104 + 80 + c * 2) = 0u;
    }
    __syncthreads();

    // ---- PV: out tile 32x160 per wave, contraction over j (96, padded) ----
    f32x4 o[2][10];
#pragma unroll
    for (int i = 0; i < 2; ++i)
#pragma unroll
        for (int nf = 0; nf < 10; ++nf) o[i][nf] = zero;

    const unsigned short* vth_base = vt_hi + ((size_t)b * CC + h * DH) * 96;
    const unsigned short* vtl_base = vt_lo + ((size_t)b * CC + h * DH) * 96;

#pragma unroll
    for (int ks = 0; ks < 3; ++ks) {
        bf16x8 pah[2], pal[2];
#pragma unroll
        for (int i = 0; i < 2; ++i) {
            pah[i] = *(const bf16x8*)(Phi + (wave * 32 + i * 16 + fr) * 104 + ks * 32 + kb);
            pal[i] = *(const bf16x8*)(Plo + (wave * 32 + i * 16 + fr) * 104 + ks * 32 + kb);
        }
#pragma unroll
        for (int nf = 0; nf < 10; ++nf) {
            bf16x8 vh = *(const bf16x8*)(vth_base + (size_t)(nf * 16 + fr) * 96 + ks * 32 + kb);
            bf16x8 vl = *(const bf16x8*)(vtl_base + (size_t)(nf * 16 + fr) * 96 + ks * 32 + kb);
#pragma unroll
            for (int i = 0; i < 2; ++i) {
                o[i][nf] = __builtin_amdgcn_mfma_f32_16x16x32_bf16(pah[i], vh, o[i][nf], 0, 0, 0);
                o[i][nf] = __builtin_amdgcn_mfma_f32_16x16x32_bf16(pah[i], vl, o[i][nf], 0, 0, 0);
                o[i][nf] = __builtin_amdgcn_mfma_f32_16x16x32_bf16(pal[i], vh, o[i][nf], 0, 0, 0);
            }
        }
    }

    // ---- epilogue: normalize + split-bf16 write ----
#pragma unroll
    for (int i = 0; i < 2; ++i)
#pragma unroll
        for (int nf = 0; nf < 10; ++nf)
#pragma unroll
            for (int r = 0; r < 4; ++r) {
                size_t rowg = qrow0 + i * 16 + g * 4 + r;
                int colg = h * DH + nf * 16 + fc;
                float val = o[i][nf][r] * inv_[i][r];
                unsigned short vh_, vl_;
                split_bf16(val, vh_, vl_);
                att_hi[rowg * CC + colg] = vh_;
                att_lo[rowg * CC + colg] = vl_;
            }
}

// ---------------------------------------------------------------------------
// Workspace (120,094,720 B), phase-overlapped:
//   [0,6.55M)       Wq splits  -> (after q-gemm) enc splits [0,5.05M)
//   [6.55M,13.1M)   Wo splits                    (live to end)
//   [13.1M,23.6M)   Wk_hi|Wk_lo|Wv_hi|Wv_lo      -> vt_lo over Wk [13.1M,17.0M)
//   [23.6M,107.5M)  hid splits -> att splits
//   [107.5M,113.8M) k_ws fp32 [1232][1280]
//   [113.8M,117.7M) vt_hi [16][1280][96]
// q splits live in d_out (2 x 41.94MB) until o-gemm overwrites it.
// ---------------------------------------------------------------------------
extern "C" void kernel_launch(void* const* d_in, const int* in_sizes, int n_in,
                              void* d_out, int out_size, void* d_ws, size_t ws_size,
                              hipStream_t stream) {
    const float* hidden = (const float*)d_in[0];
    const float* enc    = (const float*)d_in[1];
    const float* Wq     = (const float*)d_in[2];
    const float* Wk     = (const float*)d_in[3];
    const float* Wv     = (const float*)d_in[4];
    const float* Wo     = (const float*)d_in[5];
    const float* bo     = (const float*)d_in[6];
    const float* q_down = (const float*)d_in[7];
    const float* q_up   = (const float*)d_in[8];
    const float* k_down = (const float*)d_in[9];
    const float* k_up   = (const float*)d_in[10];
    const float* v_down = (const float*)d_in[11];
    const float* v_up   = (const float*)d_in[12];
    const float* o_down = (const float*)d_in[13];
    const float* o_up   = (const float*)d_in[14];

    char* ws = (char*)d_ws;
    unsigned short* Wq_hi  = (unsigned short*)(ws);
    unsigned short* Wq_lo  = (unsigned short*)(ws + 3276800);
    unsigned short* Wo_hi  = (unsigned short*)(ws + 6553600);
    unsigned short* Wo_lo  = (unsigned short*)(ws + 9830400);
    unsigned short* Wk_hi  = (unsigned short*)(ws + 13107200);
    unsigned short* Wk_lo  = (unsigned short*)(ws + 15728640);
    unsigned short* Wv_hi  = (unsigned short*)(ws + 18350080);
    unsigned short* Wv_lo  = (unsigned short*)(ws + 20971520);
    unsigned short* hid_hi = (unsigned short*)(ws + 23592960);
    unsigned short* hid_lo = (unsigned short*)(ws + 65536000);
    float*          k_ws   = (float*)(ws + 107479040);
    unsigned short* vt_hi  = (unsigned short*)(ws + 113786880);
    unsigned short* vt_lo  = (unsigned short*)(ws + 13107200);  // over dead Wk splits
    unsigned short* enc_hi = (unsigned short*)(ws);             // over dead Wq splits
    unsigned short* enc_lo = (unsigned short*)(ws + 2523136);
    unsigned short* att_hi = hid_hi;
    unsigned short* att_lo = hid_lo;
    unsigned short* q_hi   = (unsigned short*)d_out;
    unsigned short* q_lo   = q_hi + (size_t)20971520;

    const int M1 = BB * SQ;    // 16384
    const int M2 = BB * SENC;  // 1232

    dim3 blk(256);
    fold_split_kernel<<<1600, blk, 0, stream>>>(Wq, q_up, q_down, Wq_hi, Wq_lo, CC, CC);
    fold_split_kernel<<<1600, blk, 0, stream>>>(Wo, o_up, o_down, Wo_hi, Wo_lo, CC, CC);
    fold_split_kernel<<<1280, blk, 0, stream>>>(Wk, k_up, k_down, Wk_hi, Wk_lo, CC, CENC);
    fold_split_kernel<<<1280, blk, 0, stream>>>(Wv, v_up, v_down, Wv_hi, Wv_lo, CC, CENC);
    split_kernel<<<20480, blk, 0, stream>>>(hidden, hid_hi, hid_lo, (M1 * CC) / 4);

    // q = hidden @ Wq_eff^T -> bf16 splits in d_out
    gemm_bf16x3_kernel<1><<<dim3(CC / GBN, M1 / GBM), blk, 0, stream>>>(
        hid_hi, hid_lo, Wq_hi, Wq_lo, nullptr, nullptr, q_hi, q_lo, M1, CC, CC);

    // enc splits (over dead Wq splits)
    split_kernel<<<1232, blk, 0, stream>>>(enc, enc_hi, enc_lo, (M2 * CENC) / 4);

    // k = enc @ Wk_eff^T -> fp32 [1232][1280]
    gemm_bf16x3_kernel<0><<<dim3(CC / GBN, (M2 + GBM - 1) / GBM), blk, 0, stream>>>(
        enc_hi, enc_lo, Wk_hi, Wk_lo, nullptr, k_ws, nullptr, nullptr, M2, CC, CENC);

    // v = enc @ Wv_eff^T -> transposed splits vt[b][c][j]
    gemm_bf16x3_kernel<2><<<dim3(CC / GBN, (M2 + GBM - 1) / GBM), blk, 0, stream>>>(
        enc_hi, enc_lo, Wv_hi, Wv_lo, nullptr, nullptr, vt_hi, vt_lo, M2, CC, CENC);

    // attention -> att splits (over dead hid splits)
    attn_mfma_kernel<<<BB * NH * 8, blk, 0, stream>>>(
        q_hi, q_lo, k_ws, vt_hi, vt_lo, att_hi, att_lo);

    // out = att @ Wo_eff^T + bo -> fp32 d_out (q splits dead)
    gemm_bf16x3_kernel<0><<<dim3(CC / GBN, M1 / GBM), blk, 0, stream>>>(
        att_hi, att_lo, Wo_hi, Wo_lo, bo, (float*)d_out, nullptr, nullptr, M1, CC, CC);
}

// Round 5
// 527.935 us; speedup vs baseline: 3.7983x; 1.4474x over previous
//
#include <hip/hip_runtime.h>

// Problem constants
#define NH    8
#define BB    16
#define SQ    1024
#define CC    1280
#define SENC  77
#define CENC  1024
#define DH    160
#define RANK  4

typedef __attribute__((ext_vector_type(8))) short bf16x8;
typedef __attribute__((ext_vector_type(4))) float f32x4;

// ---------------------------------------------------------------------------
// fp32 -> bf16 hi/lo split (truncation; hi+lo captures ~16 mantissa bits)
// ---------------------------------------------------------------------------
__device__ inline void split_bf16(float a, unsigned short& hi, unsigned short& lo) {
    unsigned u = __float_as_uint(a);
    hi = (unsigned short)(u >> 16);
    float fhi = __uint_as_float(u & 0xffff0000u);
    float r = a - fhi;
    lo = (unsigned short)(__float_as_uint(r) >> 16);
}

// ---------------------------------------------------------------------------
// Weight fold (fp32 out): Weff = W + up@down
// ---------------------------------------------------------------------------
__global__ void fold_kernel(const float* __restrict__ W,
                            const float* __restrict__ up,
                            const float* __restrict__ down,
                            float* __restrict__ out, int N, int K) {
    int idx4 = blockIdx.x * blockDim.x + threadIdx.x;
    int total4 = (N * K) >> 2;
    if (idx4 >= total4) return;
    int i = idx4 << 2;
    int n = i / K;
    int kk = i - n * K;
    float4 acc = *(const float4*)(W + i);
#pragma unroll
    for (int r = 0; r < RANK; ++r) {
        float u = up[n * RANK + r];
        float4 dv = *(const float4*)(down + (size_t)r * K + kk);
        acc.x += u * dv.x; acc.y += u * dv.y;
        acc.z += u * dv.z; acc.w += u * dv.w;
    }
    *(float4*)(out + i) = acc;
}

// ---------------------------------------------------------------------------
// Weight fold + bf16 hi/lo split
// ---------------------------------------------------------------------------
__global__ void fold_split_kernel(const float* __restrict__ W,
                                  const float* __restrict__ up,
                                  const float* __restrict__ down,
                                  unsigned short* __restrict__ ohi,
                                  unsigned short* __restrict__ olo,
                                  int N, int K) {
    int idx4 = blockIdx.x * blockDim.x + threadIdx.x;
    int total4 = (N * K) >> 2;
    if (idx4 >= total4) return;
    int i = idx4 << 2;
    int n = i / K;
    int kk = i - n * K;
    float4 acc = *(const float4*)(W + i);
#pragma unroll
    for (int r = 0; r < RANK; ++r) {
        float u = up[n * RANK + r];
        float4 dv = *(const float4*)(down + (size_t)r * K + kk);
        acc.x += u * dv.x; acc.y += u * dv.y;
        acc.z += u * dv.z; acc.w += u * dv.w;
    }
    unsigned short h0, h1, h2, h3, l0, l1, l2, l3;
    split_bf16(acc.x, h0, l0); split_bf16(acc.y, h1, l1);
    split_bf16(acc.z, h2, l2); split_bf16(acc.w, h3, l3);
    int2 hv, lv;
    hv.x = (int)((unsigned)h0 | ((unsigned)h1 << 16));
    hv.y = (int)((unsigned)h2 | ((unsigned)h3 << 16));
    lv.x = (int)((unsigned)l0 | ((unsigned)l1 << 16));
    lv.y = (int)((unsigned)l2 | ((unsigned)l3 << 16));
    *(int2*)(ohi + i) = hv;
    *(int2*)(olo + i) = lv;
}

// ---------------------------------------------------------------------------
// Activation fp32 -> bf16 hi/lo split
// ---------------------------------------------------------------------------
__global__ void split_kernel(const float* __restrict__ x,
                             unsigned short* __restrict__ ohi,
                             unsigned short* __restrict__ olo, int total4) {
    int idx4 = blockIdx.x * blockDim.x + threadIdx.x;
    if (idx4 >= total4) return;
    int i = idx4 << 2;
    float4 a = *(const float4*)(x + i);
    unsigned short h0, h1, h2, h3, l0, l1, l2, l3;
    split_bf16(a.x, h0, l0); split_bf16(a.y, h1, l1);
    split_bf16(a.z, h2, l2); split_bf16(a.w, h3, l3);
    int2 hv, lv;
    hv.x = (int)((unsigned)h0 | ((unsigned)h1 << 16));
    hv.y = (int)((unsigned)h2 | ((unsigned)h3 << 16));
    lv.x = (int)((unsigned)l0 | ((unsigned)l1 << 16));
    lv.y = (int)((unsigned)l2 | ((unsigned)l3 << 16));
    *(int2*)(ohi + i) = hv;
    *(int2*)(olo + i) = lv;
}

// ---------------------------------------------------------------------------
// Transpose + split: out[i][j] = split(in[j][i]), 1280x1280, LDS 32x33 tiles
// ---------------------------------------------------------------------------
__global__ __launch_bounds__(256) void transpose_split_kernel(
    const float* __restrict__ in,
    unsigned short* __restrict__ ohi, unsigned short* __restrict__ olo) {
    __shared__ float t[32][33];
    int tx = threadIdx.x & 31, ty = threadIdx.x >> 5;
    int bx = blockIdx.x, by = blockIdx.y;
#pragma unroll
    for (int r = 0; r < 4; ++r)
        t[ty + 8 * r][tx] = in[(size_t)(by * 32 + ty + 8 * r) * 1280 + bx * 32 + tx];
    __syncthreads();
#pragma unroll
    for (int r = 0; r < 4; ++r) {
        float v = t[tx][ty + 8 * r];
        unsigned short h_, l_;
        split_bf16(v, h_, l_);
        size_t o = (size_t)(bx * 32 + ty + 8 * r) * 1280 + by * 32 + tx;
        ohi[o] = h_; olo[o] = l_;
    }
}

// ---------------------------------------------------------------------------
// Generalized MFMA split-bf16 GEMM: C[m][n] = sum_k A[m][k]*W[n][k]
// (A_hi*W_hi + A_hi*W_lo + A_lo*W_hi; proven 128x128/BK=32/4-wave inner loop)
// MODE 0 kv  : grid(nt,mt); splits out (ldo), row-guarded
// MODE 1 Nh  : grid(nt,1,z=b*8+h); A=K_h[b] (M=77), W=WqT+h*160; out Nbig rows
//              h*80+j (zeros j=77..79)
// MODE 2 Mh  : grid(1,mt,z); A=Wo+h*160, W=V_h[b] (N=77); out MbigT cols h*80+j
// MODE 3 S   : grid(640) T1-swizzled; W=Nbig[b]; fp32 out
// MODE 4 o   : grid(1280) T1-swizzled; W=MbigT[b]; fp32 out + bias
// ---------------------------------------------------------------------------
#define GBM 128
#define GBN 128
#define GBK 32

__device__ inline void async_load16(const void* gsrc, void* lds_dst) {
    __builtin_amdgcn_global_load_lds(
        (const __attribute__((address_space(1))) void*)gsrc,
        (__attribute__((address_space(3))) void*)lds_dst, 16, 0, 0);
}

__device__ inline int clampi(int x, int hi) { return x > hi ? hi : x; }

template <int MODE>
__global__ __launch_bounds__(256) void gemm2_kernel(
    const unsigned short* __restrict__ A_hi, const unsigned short* __restrict__ A_lo,
    int lda,
    const unsigned short* __restrict__ W_hi, const unsigned short* __restrict__ W_lo,
    int ldw,
    const float* __restrict__ bias, float* __restrict__ outF,
    unsigned short* __restrict__ oHi, unsigned short* __restrict__ oLo, int ldo,
    int M, int N, int K) {
    __shared__ __align__(16) unsigned short lds[4][GBM][GBK];
    const int tid  = threadIdx.x;
    const int wave = tid >> 6;
    const int lane = tid & 63;

    int m0, n0;
    if constexpr (MODE == 0) {
        n0 = blockIdx.x * GBN; m0 = blockIdx.y * GBM;
    } else if constexpr (MODE == 1) {
        n0 = blockIdx.x * GBN; m0 = 0;
        int z = blockIdx.z, b = z >> 3, hh = z & 7;
        size_t ao = (size_t)(b * SENC) * lda + hh * DH;
        A_hi += ao; A_lo += ao;
        W_hi += hh * DH; W_lo += hh * DH;
        size_t ob = (size_t)(b * 640 + hh * 80) * ldo;
        oHi += ob; oLo += ob;
    } else if constexpr (MODE == 2) {
        n0 = 0; m0 = blockIdx.y * GBM;
        int z = blockIdx.z, b = z >> 3, hh = z & 7;
        A_hi += hh * DH; A_lo += hh * DH;
        size_t wo = (size_t)(b * SENC) * ldw + CC + hh * DH;
        W_hi += wo; W_lo += wo;
        size_t ob = (size_t)b * CC * ldo + hh * 80;
        oHi += ob; oLo += ob;
    } else if constexpr (MODE == 3) {
        int bid = blockIdx.x;                       // 640 blocks, T1 bijective
        int w = (bid & 7) * 80 + (bid >> 3);
        int mt = w / 5, nt = w - mt * 5;
        m0 = mt * GBM; n0 = nt * GBN;
        int b = m0 >> 10;
        size_t wo = (size_t)b * 640 * ldw;
        W_hi += wo; W_lo += wo;
    } else {
        int bid = blockIdx.x;                       // 1280 blocks, T1 bijective
        int w = (bid & 7) * 160 + (bid >> 3);
        int mt = w / 10, nt = w - mt * 10;
        m0 = mt * GBM; n0 = nt * GBN;
        int b = m0 >> 10;
        size_t wo = (size_t)b * CC * ldw;
        W_hi += wo; W_lo += wo;
    }

    const int wr = wave >> 1, wc = wave & 1;
    f32x4 zero = {0.f, 0.f, 0.f, 0.f};
    f32x4 acc[4][4];
#pragma unroll
    for (int i = 0; i < 4; ++i)
#pragma unroll
        for (int j = 0; j < 4; ++j) acc[i][j] = zero;

    const int c0 = wave * 2, c1 = wave * 2 + 1;
    const int rr = lane >> 2;
    const int kc = (lane & 3) * 8;
    const int ra0 = clampi(m0 + c0 * 16 + rr, M - 1);
    const int ra1 = clampi(m0 + c1 * 16 + rr, M - 1);
    const int rw0 = clampi(n0 + c0 * 16 + rr, N - 1);
    const int rw1 = clampi(n0 + c1 * 16 + rr, N - 1);
    const unsigned short* pAh0 = A_hi + (size_t)ra0 * lda + kc;
    const unsigned short* pAh1 = A_hi + (size_t)ra1 * lda + kc;
    const unsigned short* pAl0 = A_lo + (size_t)ra0 * lda + kc;
    const unsigned short* pAl1 = A_lo + (size_t)ra1 * lda + kc;
    const unsigned short* pWh0 = W_hi + (size_t)rw0 * ldw + kc;
    const unsigned short* pWh1 = W_hi + (size_t)rw1 * ldw + kc;
    const unsigned short* pWl0 = W_lo + (size_t)rw0 * ldw + kc;
    const unsigned short* pWl1 = W_lo + (size_t)rw1 * ldw + kc;

    for (int k0 = 0; k0 < K; k0 += GBK) {
        async_load16(pAh0 + k0, &lds[0][c0 * 16][0]);
        async_load16(pAh1 + k0, &lds[0][c1 * 16][0]);
        async_load16(pAl0 + k0, &lds[1][c0 * 16][0]);
        async_load16(pAl1 + k0, &lds[1][c1 * 16][0]);
        async_load16(pWh0 + k0, &lds[2][c0 * 16][0]);
        async_load16(pWh1 + k0, &lds[2][c1 * 16][0]);
        async_load16(pWl0 + k0, &lds[3][c0 * 16][0]);
        async_load16(pWl1 + k0, &lds[3][c1 * 16][0]);
        __syncthreads();

        bf16x8 ah[4], al[4], bh[4], bl[4];
        const int fr = lane & 15;
        const int kb = (lane >> 4) * 8;
#pragma unroll
        for (int i = 0; i < 4; ++i) {
            ah[i] = *(const bf16x8*)&lds[0][wr * 64 + i * 16 + fr][kb];
            al[i] = *(const bf16x8*)&lds[1][wr * 64 + i * 16 + fr][kb];
            bh[i] = *(const bf16x8*)&lds[2][wc * 64 + i * 16 + fr][kb];
            bl[i] = *(const bf16x8*)&lds[3][wc * 64 + i * 16 + fr][kb];
        }
#pragma unroll
        for (int i = 0; i < 4; ++i)
#pragma unroll
            for (int j = 0; j < 4; ++j) {
                acc[i][j] = __builtin_amdgcn_mfma_f32_16x16x32_bf16(ah[i], bh[j], acc[i][j], 0, 0, 0);
                acc[i][j] = __builtin_amdgcn_mfma_f32_16x16x32_bf16(ah[i], bl[j], acc[i][j], 0, 0, 0);
                acc[i][j] = __builtin_amdgcn_mfma_f32_16x16x32_bf16(al[i], bh[j], acc[i][j], 0, 0, 0);
            }
        __syncthreads();
    }

    // C/D layout: col=lane&15, row=(lane>>4)*4+reg  [m89-verified]
    const int fc = lane & 15;
    const int fr4 = (lane >> 4) * 4;
#pragma unroll
    for (int j = 0; j < 4; ++j) {
        int col = n0 + wc * 64 + j * 16 + fc;
        float bv = 0.f;
        if constexpr (MODE == 4) bv = bias[col];
#pragma unroll
        for (int i = 0; i < 4; ++i) {
            int row = m0 + wr * 64 + i * 16 + fr4;
#pragma unroll
            for (int r = 0; r < 4; ++r) {
                int rowr = row + r;
                float val = acc[i][j][r];
                if constexpr (MODE == 0) {
                    if (rowr < M) {
                        unsigned short vh, vl;
                        split_bf16(val, vh, vl);
                        oHi[(size_t)rowr * ldo + col] = vh;
                        oLo[(size_t)rowr * ldo + col] = vl;
                    }
                } else if constexpr (MODE == 1) {
                    if (rowr < 80) {
                        if (rowr >= SENC) val = 0.f;
                        unsigned short vh, vl;
                        split_bf16(val, vh, vl);
                        oHi[(size_t)rowr * ldo + col] = vh;
                        oLo[(size_t)rowr * ldo + col] = vl;
                    }
                } else if constexpr (MODE == 2) {
                    if (col < 80) {
                        if (col >= SENC) val = 0.f;
                        unsigned short vh, vl;
                        split_bf16(val, vh, vl);
                        oHi[(size_t)rowr * ldo + col] = vh;
                        oLo[(size_t)rowr * ldo + col] = vl;
                    }
                } else if constexpr (MODE == 3) {
                    outF[(size_t)rowr * ldo + col] = val;
                } else {
                    outF[(size_t)rowr * ldo + col] = val + bv;
                }
            }
        }
    }
}

// ---------------------------------------------------------------------------
// Softmax over S: per (row, head) 80-col block, valid j<77, scale 1/sqrt(160).
// 4 lanes cooperate per (row,head); output P as bf16 splits (zeros at j>=77).
// ---------------------------------------------------------------------------
__global__ __launch_bounds__(256) void softmax_kernel(
    const float* __restrict__ S,
    unsigned short* __restrict__ Phi, unsigned short* __restrict__ Plo) {
    const float scale = 0.07905694150420949f;  // 1/sqrt(160)
    int t = blockIdx.x * 256 + threadIdx.x;    // 524288 threads
    int li = t & 3;
    int g = t >> 2;                            // 131072 row-heads
    int row = g >> 3, h = g & 7;
    const float* p = S + (size_t)row * 640 + h * 80;

    float v[20];
#pragma unroll
    for (int m = 0; m < 5; ++m) {
        float4 x = *(const float4*)(p + (li + 4 * m) * 4);
        v[m * 4 + 0] = x.x; v[m * 4 + 1] = x.y;
        v[m * 4 + 2] = x.z; v[m * 4 + 3] = x.w;
    }
    float mx = -1e30f;
#pragma unroll
    for (int m = 0; m < 5; ++m)
#pragma unroll
        for (int e = 0; e < 4; ++e) {
            int j = (li + 4 * m) * 4 + e;
            float x = v[m * 4 + e] * scale;
            v[m * 4 + e] = x;
            if (j < SENC) mx = fmaxf(mx, x);
        }
    mx = fmaxf(mx, __shfl_xor(mx, 1));
    mx = fmaxf(mx, __shfl_xor(mx, 2));
    float sum = 0.f;
#pragma unroll
    for (int m = 0; m < 5; ++m)
#pragma unroll
        for (int e = 0; e < 4; ++e) {
            int j = (li + 4 * m) * 4 + e;
            float ex = (j < SENC) ? __expf(v[m * 4 + e] - mx) : 0.f;
            v[m * 4 + e] = ex;
            sum += ex;
        }
    sum += __shfl_xor(sum, 1);
    sum += __shfl_xor(sum, 2);
    float inv = 1.f / sum;

    size_t ob = (size_t)row * 640 + h * 80;
#pragma unroll
    for (int m = 0; m < 5; ++m) {
        unsigned short hh[4], ll[4];
#pragma unroll
        for (int e = 0; e < 4; ++e) split_bf16(v[m * 4 + e] * inv, hh[e], ll[e]);
        ushort4 hv; hv.x = hh[0]; hv.y = hh[1]; hv.z = hh[2]; hv.w = hh[3];
        ushort4 lv; lv.x = ll[0]; lv.y = ll[1]; lv.z = ll[2]; lv.w = ll[3];
        *(ushort4*)(Phi + ob + (li + 4 * m) * 4) = hv;
        *(ushort4*)(Plo + ob + (li + 4 * m) * 4) = lv;
    }
}

// ---------------------------------------------------------------------------
// Workspace (byte offsets; peak 113,541,120 <= 120,094,720):
//   Wo_sp   [0, 6.55M)                        live: -> Mh
//   kv_sp   [6,553,600, 19,169,280)           live: kv-gemm -> Mh
//   Wkv_sp  [19,169,280, 29,655,040)          dead after kv-gemm
//   Nbig_sp [19,169,280, 71,598,080)          live: Nh -> S-gemm (over Wkv)
//   P_sp    [19,169,280, 61,112,320)          live: softmax -> o-gemm (over Nbig)
//   MbigT   [61,112,320, 113,541,120)         live: Mh -> o-gemm (over S tail)
//   S_f32   [71,598,080, 113,541,120)         live: S-gemm -> softmax
//   WqT_sp  [71,598,080, 78,151,680)          dead after Nh (under S)
//   Wq_f32  [78,151,680, 84,705,280)          dead after transpose (under S)
//   enc_sp  [84,705,280, 89,751,552)          dead after kv-gemm (under S)
// hidden splits live in d_out until the final o-gemm overwrites it.
// ---------------------------------------------------------------------------
extern "C" void kernel_launch(void* const* d_in, const int* in_sizes, int n_in,
                              void* d_out, int out_size, void* d_ws, size_t ws_size,
                              hipStream_t stream) {
    const float* hidden = (const float*)d_in[0];
    const float* enc    = (const float*)d_in[1];
    const float* Wq     = (const float*)d_in[2];
    const float* Wk     = (const float*)d_in[3];
    const float* Wv     = (const float*)d_in[4];
    const float* Wo     = (const float*)d_in[5];
    const float* bo     = (const float*)d_in[6];
    const float* q_down = (const float*)d_in[7];
    const float* q_up   = (const float*)d_in[8];
    const float* k_down = (const float*)d_in[9];
    const float* k_up   = (const float*)d_in[10];
    const float* v_down = (const float*)d_in[11];
    const float* v_up   = (const float*)d_in[12];
    const float* o_down = (const float*)d_in[13];
    const float* o_up   = (const float*)d_in[14];

    char* ws = (char*)d_ws;
    unsigned short* Wo_hi   = (unsigned short*)(ws);
    unsigned short* Wo_lo   = (unsigned short*)(ws + 3276800);
    unsigned short* kv_hi   = (unsigned short*)(ws + 6553600);
    unsigned short* kv_lo   = (unsigned short*)(ws + 12861440);
    unsigned short* Wkv_hi  = (unsigned short*)(ws + 19169280);
    unsigned short* Wkv_lo  = (unsigned short*)(ws + 24412160);
    unsigned short* Nbig_hi = (unsigned short*)(ws + 19169280);
    unsigned short* Nbig_lo = (unsigned short*)(ws + 45383680);
    unsigned short* P_hi    = (unsigned short*)(ws + 19169280);
    unsigned short* P_lo    = (unsigned short*)(ws + 40140800);
    unsigned short* MbT_hi  = (unsigned short*)(ws + 61112320);
    unsigned short* MbT_lo  = (unsigned short*)(ws + 87326720);
    float*          S_f32   = (float*)(ws + 71598080);
    unsigned short* WqT_hi  = (unsigned short*)(ws + 71598080);
    unsigned short* WqT_lo  = (unsigned short*)(ws + 74874880);
    float*          Wq_f32  = (float*)(ws + 78151680);
    unsigned short* enc_hi  = (unsigned short*)(ws + 84705280);
    unsigned short* enc_lo  = (unsigned short*)(ws + 87228416);
    unsigned short* hid_hi  = (unsigned short*)d_out;
    unsigned short* hid_lo  = hid_hi + (size_t)20971520;

    const int M1 = BB * SQ;    // 16384
    const int M2 = BB * SENC;  // 1232

    dim3 blk(256);
    // ---- weight prep ----
    fold_split_kernel<<<1600, blk, 0, stream>>>(Wo, o_up, o_down, Wo_hi, Wo_lo, CC, CC);
    fold_kernel<<<1600, blk, 0, stream>>>(Wq, q_up, q_down, Wq_f32, CC, CC);
    transpose_split_kernel<<<dim3(40, 40), blk, 0, stream>>>(Wq_f32, WqT_hi, WqT_lo);
    fold_split_kernel<<<1280, blk, 0, stream>>>(Wk, k_up, k_down, Wkv_hi, Wkv_lo, CC, CENC);
    fold_split_kernel<<<1280, blk, 0, stream>>>(Wv, v_up, v_down,
                                                Wkv_hi + 1310720, Wkv_lo + 1310720, CC, CENC);
    // ---- activation splits ----
    split_kernel<<<1232, blk, 0, stream>>>(enc, enc_hi, enc_lo, (M2 * CENC) / 4);
    split_kernel<<<20480, blk, 0, stream>>>(hidden, hid_hi, hid_lo, (M1 * CC) / 4);

    // ---- kv = enc @ [Wk|Wv]_eff^T -> kv splits [1232][2560] ----
    gemm2_kernel<0><<<dim3(20, 10), blk, 0, stream>>>(
        enc_hi, enc_lo, CENC, Wkv_hi, Wkv_lo, CENC,
        nullptr, nullptr, kv_hi, kv_lo, 2560, M2, 2560, CENC);

    // ---- Nh[b,h] = K_h[b] @ Wq_h  -> Nbig splits [16][640][1280] ----
    gemm2_kernel<1><<<dim3(10, 1, 128), blk, 0, stream>>>(
        kv_hi, kv_lo, 2560, WqT_hi, WqT_lo, CC,
        nullptr, nullptr, Nbig_hi, Nbig_lo, CC, SENC, CC, DH);

    // ---- S = hidden @ Nbig[b]^T -> fp32 [16384][640] ----
    gemm2_kernel<3><<<640, blk, 0, stream>>>(
        hid_hi, hid_lo, CC, Nbig_hi, Nbig_lo, CC,
        nullptr, S_f32, nullptr, nullptr, 640, M1, 640, CC);

    // ---- softmax -> P splits [16384][640] ----
    softmax_kernel<<<2048, blk, 0, stream>>>(S_f32, P_hi, P_lo);

    // ---- MhT[b,h] = Wo_eff[:,h] @ V_h[b]^T -> MbigT splits [16][1280][640] ----
    gemm2_kernel<2><<<dim3(1, 10, 128), blk, 0, stream>>>(
        Wo_hi, Wo_lo, CC, kv_hi, kv_lo, 2560,
        nullptr, nullptr, MbT_hi, MbT_lo, 640, CC, SENC, DH);

    // ---- out = P @ MbigT[b]^T + bo -> fp32 d_out ----
    gemm2_kernel<4><<<1280, blk, 0, stream>>>(
        P_hi, P_lo, 640, MbT_hi, MbT_lo, 640,
        bo, (float*)d_out, nullptr, nullptr, CC, M1, CC, 640);
}

// Round 6
// 484.678 us; speedup vs baseline: 4.1372x; 1.0892x over previous
//
#include <hip/hip_runtime.h>

// Problem constants
#define NH    8
#define BB    16
#define SQ    1024
#define CC    1280
#define SENC  77
#define CENC  1024
#define DH    160
#define RANK  4

typedef __attribute__((ext_vector_type(8))) short bf16x8;
typedef __attribute__((ext_vector_type(4))) float f32x4;

// ---------------------------------------------------------------------------
// fp32 -> bf16 hi/lo split (truncation; hi+lo captures ~16 mantissa bits)
// ---------------------------------------------------------------------------
__device__ inline void split_bf16(float a, unsigned short& hi, unsigned short& lo) {
    unsigned u = __float_as_uint(a);
    hi = (unsigned short)(u >> 16);
    float fhi = __uint_as_float(u & 0xffff0000u);
    float r = a - fhi;
    lo = (unsigned short)(__float_as_uint(r) >> 16);
}

// ---------------------------------------------------------------------------
// Weight fold + bf16 hi/lo split (Wo)
// ---------------------------------------------------------------------------
__global__ void fold_split_kernel(const float* __restrict__ W,
                                  const float* __restrict__ up,
                                  const float* __restrict__ down,
                                  unsigned short* __restrict__ ohi,
                                  unsigned short* __restrict__ olo,
                                  int N, int K) {
    int idx4 = blockIdx.x * blockDim.x + threadIdx.x;
    int total4 = (N * K) >> 2;
    if (idx4 >= total4) return;
    int i = idx4 << 2;
    int n = i / K;
    int kk = i - n * K;
    float4 acc = *(const float4*)(W + i);
#pragma unroll
    for (int r = 0; r < RANK; ++r) {
        float u = up[n * RANK + r];
        float4 dv = *(const float4*)(down + (size_t)r * K + kk);
        acc.x += u * dv.x; acc.y += u * dv.y;
        acc.z += u * dv.z; acc.w += u * dv.w;
    }
    unsigned short h0, h1, h2, h3, l0, l1, l2, l3;
    split_bf16(acc.x, h0, l0); split_bf16(acc.y, h1, l1);
    split_bf16(acc.z, h2, l2); split_bf16(acc.w, h3, l3);
    int2 hv, lv;
    hv.x = (int)((unsigned)h0 | ((unsigned)h1 << 16));
    hv.y = (int)((unsigned)h2 | ((unsigned)h3 << 16));
    lv.x = (int)((unsigned)l0 | ((unsigned)l1 << 16));
    lv.y = (int)((unsigned)l2 | ((unsigned)l3 << 16));
    *(int2*)(ohi + i) = hv;
    *(int2*)(olo + i) = lv;
}

// ---------------------------------------------------------------------------
// Combined Wk|Wv fold + split into one [2560][1024] buffer
// ---------------------------------------------------------------------------
__global__ void fold_split_kv_kernel(const float* __restrict__ Wk,
                                     const float* __restrict__ Wv,
                                     const float* __restrict__ k_up,
                                     const float* __restrict__ k_down,
                                     const float* __restrict__ v_up,
                                     const float* __restrict__ v_down,
                                     unsigned short* __restrict__ ohi,
                                     unsigned short* __restrict__ olo) {
    int idx4 = blockIdx.x * blockDim.x + threadIdx.x;   // 655360 total
    int i = idx4 << 2;
    int n = i >> 10;            // K = 1024
    int kk = i & 1023;
    const float* W; const float* up; const float* down; int nn = n;
    if (n < CC) { W = Wk; up = k_up; down = k_down; }
    else        { W = Wv; up = v_up; down = v_down; nn = n - CC; }
    float4 acc = *(const float4*)(W + (size_t)nn * CENC + kk);
#pragma unroll
    for (int r = 0; r < RANK; ++r) {
        float u = up[nn * RANK + r];
        float4 dv = *(const float4*)(down + (size_t)r * CENC + kk);
        acc.x += u * dv.x; acc.y += u * dv.y;
        acc.z += u * dv.z; acc.w += u * dv.w;
    }
    unsigned short h0, h1, h2, h3, l0, l1, l2, l3;
    split_bf16(acc.x, h0, l0); split_bf16(acc.y, h1, l1);
    split_bf16(acc.z, h2, l2); split_bf16(acc.w, h3, l3);
    int2 hv, lv;
    hv.x = (int)((unsigned)h0 | ((unsigned)h1 << 16));
    hv.y = (int)((unsigned)h2 | ((unsigned)h3 << 16));
    lv.x = (int)((unsigned)l0 | ((unsigned)l1 << 16));
    lv.y = (int)((unsigned)l2 | ((unsigned)l3 << 16));
    *(int2*)(ohi + i) = hv;
    *(int2*)(olo + i) = lv;
}

// ---------------------------------------------------------------------------
// Fused Wq fold + transpose + split: WqT[k][n] = split(Wq_eff[n][k])
// ---------------------------------------------------------------------------
__global__ __launch_bounds__(256) void foldT_split_kernel(
    const float* __restrict__ W, const float* __restrict__ up,
    const float* __restrict__ down,
    unsigned short* __restrict__ ohi, unsigned short* __restrict__ olo) {
    __shared__ float t[32][33];
    int tx = threadIdx.x & 31, ty = threadIdx.x >> 5;
    int bx = blockIdx.x, by = blockIdx.y;
    int k = bx * 32 + tx;
#pragma unroll
    for (int r4 = 0; r4 < 4; ++r4) {
        int n = by * 32 + ty + 8 * r4;
        float v = W[(size_t)n * 1280 + k];
#pragma unroll
        for (int r = 0; r < RANK; ++r)
            v += up[n * RANK + r] * down[r * 1280 + k];
        t[ty + 8 * r4][tx] = v;
    }
    __syncthreads();
#pragma unroll
    for (int r4 = 0; r4 < 4; ++r4) {
        float v = t[tx][ty + 8 * r4];
        unsigned short h_, l_;
        split_bf16(v, h_, l_);
        size_t o = (size_t)(bx * 32 + ty + 8 * r4) * 1280 + by * 32 + tx;
        ohi[o] = h_; olo[o] = l_;
    }
}

// ---------------------------------------------------------------------------
// Activation fp32 -> bf16 hi/lo split
// ---------------------------------------------------------------------------
__global__ void split_kernel(const float* __restrict__ x,
                             unsigned short* __restrict__ ohi,
                             unsigned short* __restrict__ olo, int total4) {
    int idx4 = blockIdx.x * blockDim.x + threadIdx.x;
    if (idx4 >= total4) return;
    int i = idx4 << 2;
    float4 a = *(const float4*)(x + i);
    unsigned short h0, h1, h2, h3, l0, l1, l2, l3;
    split_bf16(a.x, h0, l0); split_bf16(a.y, h1, l1);
    split_bf16(a.z, h2, l2); split_bf16(a.w, h3, l3);
    int2 hv, lv;
    hv.x = (int)((unsigned)h0 | ((unsigned)h1 << 16));
    hv.y = (int)((unsigned)h2 | ((unsigned)h3 << 16));
    lv.x = (int)((unsigned)l0 | ((unsigned)l1 << 16));
    lv.y = (int)((unsigned)l2 | ((unsigned)l3 << 16));
    *(int2*)(ohi + i) = hv;
    *(int2*)(olo + i) = lv;
}

// ---------------------------------------------------------------------------
// Generalized MFMA split-bf16 GEMM (proven 128x128/BK=32/4-wave inner loop)
// MODE 0 kv  | MODE 1 Nh | MODE 2 Mh | MODE 4 o-proj (T1 swizzle, bias)
// ---------------------------------------------------------------------------
#define GBM 128
#define GBN 128
#define GBK 32

__device__ inline void async_load16(const void* gsrc, void* lds_dst) {
    __builtin_amdgcn_global_load_lds(
        (const __attribute__((address_space(1))) void*)gsrc,
        (__attribute__((address_space(3))) void*)lds_dst, 16, 0, 0);
}

__device__ inline int clampi(int x, int hi) { return x > hi ? hi : x; }

template <int MODE>
__global__ __launch_bounds__(256) void gemm2_kernel(
    const unsigned short* __restrict__ A_hi, const unsigned short* __restrict__ A_lo,
    int lda,
    const unsigned short* __restrict__ W_hi, const unsigned short* __restrict__ W_lo,
    int ldw,
    const float* __restrict__ bias, float* __restrict__ outF,
    unsigned short* __restrict__ oHi, unsigned short* __restrict__ oLo, int ldo,
    int M, int N, int K) {
    __shared__ __align__(16) unsigned short lds[4][GBM][GBK];
    const int tid  = threadIdx.x;
    const int wave = tid >> 6;
    const int lane = tid & 63;

    int m0, n0;
    if constexpr (MODE == 0) {
        n0 = blockIdx.x * GBN; m0 = blockIdx.y * GBM;
    } else if constexpr (MODE == 1) {
        n0 = blockIdx.x * GBN; m0 = 0;
        int z = blockIdx.z, b = z >> 3, hh = z & 7;
        size_t ao = (size_t)(b * SENC) * lda + hh * DH;
        A_hi += ao; A_lo += ao;
        W_hi += hh * DH; W_lo += hh * DH;
        size_t ob = (size_t)(b * 640 + hh * 80) * ldo;
        oHi += ob; oLo += ob;
    } else if constexpr (MODE == 2) {
        n0 = 0; m0 = blockIdx.y * GBM;
        int z = blockIdx.z, b = z >> 3, hh = z & 7;
        A_hi += hh * DH; A_lo += hh * DH;
        size_t wo = (size_t)(b * SENC) * ldw + CC + hh * DH;
        W_hi += wo; W_lo += wo;
        size_t ob = (size_t)b * CC * ldo + hh * 80;
        oHi += ob; oLo += ob;
    } else {
        int bid = blockIdx.x;                       // 1280 blocks, T1 bijective
        int w = (bid & 7) * 160 + (bid >> 3);
        int mt = w / 10, nt = w - mt * 10;
        m0 = mt * GBM; n0 = nt * GBN;
        int b = m0 >> 10;
        size_t wo = (size_t)b * CC * ldw;
        W_hi += wo; W_lo += wo;
    }

    const int wr = wave >> 1, wc = wave & 1;
    f32x4 zero = {0.f, 0.f, 0.f, 0.f};
    f32x4 acc[4][4];
#pragma unroll
    for (int i = 0; i < 4; ++i)
#pragma unroll
        for (int j = 0; j < 4; ++j) acc[i][j] = zero;

    const int c0 = wave * 2, c1 = wave * 2 + 1;
    const int rr = lane >> 2;
    const int kc = (lane & 3) * 8;
    const int ra0 = clampi(m0 + c0 * 16 + rr, M - 1);
    const int ra1 = clampi(m0 + c1 * 16 + rr, M - 1);
    const int rw0 = clampi(n0 + c0 * 16 + rr, N - 1);
    const int rw1 = clampi(n0 + c1 * 16 + rr, N - 1);
    const unsigned short* pAh0 = A_hi + (size_t)ra0 * lda + kc;
    const unsigned short* pAh1 = A_hi + (size_t)ra1 * lda + kc;
    const unsigned short* pAl0 = A_lo + (size_t)ra0 * lda + kc;
    const unsigned short* pAl1 = A_lo + (size_t)ra1 * lda + kc;
    const unsigned short* pWh0 = W_hi + (size_t)rw0 * ldw + kc;
    const unsigned short* pWh1 = W_hi + (size_t)rw1 * ldw + kc;
    const unsigned short* pWl0 = W_lo + (size_t)rw0 * ldw + kc;
    const unsigned short* pWl1 = W_lo + (size_t)rw1 * ldw + kc;

    for (int k0 = 0; k0 < K; k0 += GBK) {
        async_load16(pAh0 + k0, &lds[0][c0 * 16][0]);
        async_load16(pAh1 + k0, &lds[0][c1 * 16][0]);
        async_load16(pAl0 + k0, &lds[1][c0 * 16][0]);
        async_load16(pAl1 + k0, &lds[1][c1 * 16][0]);
        async_load16(pWh0 + k0, &lds[2][c0 * 16][0]);
        async_load16(pWh1 + k0, &lds[2][c1 * 16][0]);
        async_load16(pWl0 + k0, &lds[3][c0 * 16][0]);
        async_load16(pWl1 + k0, &lds[3][c1 * 16][0]);
        __syncthreads();

        bf16x8 ah[4], al[4], bh[4], bl[4];
        const int fr = lane & 15;
        const int kb = (lane >> 4) * 8;
#pragma unroll
        for (int i = 0; i < 4; ++i) {
            ah[i] = *(const bf16x8*)&lds[0][wr * 64 + i * 16 + fr][kb];
            al[i] = *(const bf16x8*)&lds[1][wr * 64 + i * 16 + fr][kb];
            bh[i] = *(const bf16x8*)&lds[2][wc * 64 + i * 16 + fr][kb];
            bl[i] = *(const bf16x8*)&lds[3][wc * 64 + i * 16 + fr][kb];
        }
#pragma unroll
        for (int i = 0; i < 4; ++i)
#pragma unroll
            for (int j = 0; j < 4; ++j) {
                acc[i][j] = __builtin_amdgcn_mfma_f32_16x16x32_bf16(ah[i], bh[j], acc[i][j], 0, 0, 0);
                acc[i][j] = __builtin_amdgcn_mfma_f32_16x16x32_bf16(ah[i], bl[j], acc[i][j], 0, 0, 0);
                acc[i][j] = __builtin_amdgcn_mfma_f32_16x16x32_bf16(al[i], bh[j], acc[i][j], 0, 0, 0);
            }
        __syncthreads();
    }

    // C/D layout: col=lane&15, row=(lane>>4)*4+reg  [m89-verified]
    const int fc = lane & 15;
    const int fr4 = (lane >> 4) * 4;
#pragma unroll
    for (int j = 0; j < 4; ++j) {
        int col = n0 + wc * 64 + j * 16 + fc;
        float bv = 0.f;
        if constexpr (MODE == 4) bv = bias[col];
#pragma unroll
        for (int i = 0; i < 4; ++i) {
            int row = m0 + wr * 64 + i * 16 + fr4;
#pragma unroll
            for (int r = 0; r < 4; ++r) {
                int rowr = row + r;
                float val = acc[i][j][r];
                if constexpr (MODE == 0) {
                    if (rowr < M) {
                        unsigned short vh, vl;
                        split_bf16(val, vh, vl);
                        oHi[(size_t)rowr * ldo + col] = vh;
                        oLo[(size_t)rowr * ldo + col] = vl;
                    }
                } else if constexpr (MODE == 1) {
                    if (rowr < 80) {
                        if (rowr >= SENC) val = 0.f;
                        unsigned short vh, vl;
                        split_bf16(val, vh, vl);
                        oHi[(size_t)rowr * ldo + col] = vh;
                        oLo[(size_t)rowr * ldo + col] = vl;
                    }
                } else if constexpr (MODE == 2) {
                    if (col < 80) {
                        if (col >= SENC) val = 0.f;
                        unsigned short vh, vl;
                        split_bf16(val, vh, vl);
                        oHi[(size_t)rowr * ldo + col] = vh;
                        oLo[(size_t)rowr * ldo + col] = vl;
                    }
                } else {
                    outF[(size_t)rowr * ldo + col] = val + bv;
                }
            }
        }
    }
}

// ---------------------------------------------------------------------------
// Fused S-GEMM + softmax -> P splits.
// Tile 128x160 (BN=160 = 2 head-blocks of 80), 4 waves (2M x 2N): per-wave
// 64 rows x 80 cols (one full head-block) -> softmax is wave-local via the
// proven 16-lane shfl_xor reduction. K=1280 contraction, split-3 MFMA.
// LDS: Ah[128][32] Al[128][32] Bh[160][32] Bl[160][32] = 36,864B, staged by
// 36 1KB gload_lds chunks (9/wave) with XOR k-group swizzle (slot^=(r>>1)&3)
// applied identically on the pre-swizzled global source and the ds_read.
// Grid 512 (128 mt x 4 nt), T1 bijective XCD swizzle.
// ---------------------------------------------------------------------------
__global__ __launch_bounds__(256) void sgemm_softmax_kernel(
    const unsigned short* __restrict__ A_hi, const unsigned short* __restrict__ A_lo,
    const unsigned short* __restrict__ Nbig_hi, const unsigned short* __restrict__ Nbig_lo,
    unsigned short* __restrict__ P_hi, unsigned short* __restrict__ P_lo) {
    __shared__ __align__(16) unsigned short sLDS[18432];
    const int tid = threadIdx.x;
    const int wave = tid >> 6;
    const int lane = tid & 63;
    const int fr = lane & 15;
    const int g = lane >> 4;
    const float scale = 0.07905694150420949f;  // 1/sqrt(160)

    int bid = blockIdx.x;                      // 512 blocks
    int w = (bid & 7) * 64 + (bid >> 3);       // T1 bijective (512 % 8 == 0)
    int mt = w >> 2, nt = w & 3;
    const int m0 = mt * 128;
    const int n0 = nt * 160;
    const int b = mt >> 3;
    const unsigned short* W_hi = Nbig_hi + (size_t)b * 640 * CC;
    const unsigned short* W_lo = Nbig_lo + (size_t)b * 640 * CC;

    const int wr = wave >> 1, wc = wave & 1;

    // staging: 36 chunks (Ah 0-7, Al 8-15, Bh 16-25, Bl 26-35), wave gets 9
    const int rr = lane >> 2;
    const int kcs = ((lane & 3) ^ ((lane >> 3) & 3)) * 8;   // swizzled src k-group
    const unsigned short* gsrc[9];
    int ldst[9];
#pragma unroll
    for (int q = 0; q < 9; ++q) {
        int c = wave * 9 + q;
        const unsigned short* base; int ld, row0, toff, lc;
        if (c < 8)       { base = A_hi; ld = CC; row0 = m0; toff = 0;     lc = c; }
        else if (c < 16) { base = A_lo; ld = CC; row0 = m0; toff = 4096;  lc = c - 8; }
        else if (c < 26) { base = W_hi; ld = CC; row0 = n0; toff = 8192;  lc = c - 16; }
        else             { base = W_lo; ld = CC; row0 = n0; toff = 13312; lc = c - 26; }
        gsrc[q] = base + (size_t)(row0 + lc * 16 + rr) * ld + kcs;
        ldst[q] = toff + lc * 512;
    }

    f32x4 zero = {0.f, 0.f, 0.f, 0.f};
    f32x4 acc[4][5];
#pragma unroll
    for (int i = 0; i < 4; ++i)
#pragma unroll
        for (int j = 0; j < 5; ++j) acc[i][j] = zero;

    const int kbsw = (g ^ ((fr >> 1) & 3)) * 8;  // swizzled read k-group (const/lane)

    for (int k0 = 0; k0 < CC; k0 += 32) {
#pragma unroll
        for (int q = 0; q < 9; ++q)
            async_load16(gsrc[q] + k0, &sLDS[ldst[q]]);
        __syncthreads();

        bf16x8 ah[4], al[4];
#pragma unroll
        for (int i = 0; i < 4; ++i) {
            int r = wr * 64 + i * 16 + fr;
            ah[i] = *(const bf16x8*)&sLDS[r * 32 + kbsw];
            al[i] = *(const bf16x8*)&sLDS[4096 + r * 32 + kbsw];
        }
#pragma unroll
        for (int j = 0; j < 5; ++j) {
            int rb = wc * 80 + j * 16 + fr;
            bf16x8 bh = *(const bf16x8*)&sLDS[8192 + rb * 32 + kbsw];
            bf16x8 bl = *(const bf16x8*)&sLDS[13312 + rb * 32 + kbsw];
#pragma unroll
            for (int i = 0; i < 4; ++i) {
                acc[i][j] = __builtin_amdgcn_mfma_f32_16x16x32_bf16(ah[i], bh, acc[i][j], 0, 0, 0);
                acc[i][j] = __builtin_amdgcn_mfma_f32_16x16x32_bf16(ah[i], bl, acc[i][j], 0, 0, 0);
                acc[i][j] = __builtin_amdgcn_mfma_f32_16x16x32_bf16(al[i], bh, acc[i][j], 0, 0, 0);
            }
        }
        __syncthreads();
    }

    // softmax per row (wave-local: this wave's 80 cols = one full head block)
    // C/D: col = j*16 + fc (fc=lane&15), row = i*16 + g*4 + reg
    const int fc = fr;
    const bool maskme = (fc >= 13);  // j==4 frag: cols 77..79
#pragma unroll
    for (int i = 0; i < 4; ++i) {
#pragma unroll
        for (int r = 0; r < 4; ++r) {
            float m = -1e30f;
#pragma unroll
            for (int j = 0; j < 5; ++j) {
                float v = acc[i][j][r] * scale;
                if (j == 4 && maskme) v = -1e30f;
                acc[i][j][r] = v;
                m = fmaxf(m, v);
            }
#pragma unroll
            for (int msk = 1; msk < 16; msk <<= 1) m = fmaxf(m, __shfl_xor(m, msk));
            float sum = 0.f;
#pragma unroll
            for (int j = 0; j < 5; ++j) {
                float e = (j == 4 && maskme) ? 0.f : __expf(acc[i][j][r] - m);
                acc[i][j][r] = e;
                sum += e;
            }
#pragma unroll
            for (int msk = 1; msk < 16; msk <<= 1) sum += __shfl_xor(sum, msk);
            float inv = 1.f / sum;
            int row = m0 + wr * 64 + i * 16 + g * 4 + r;
            size_t ob = (size_t)row * 640 + n0 + wc * 80 + fc;
#pragma unroll
            for (int j = 0; j < 5; ++j) {
                unsigned short ph, pl;
                split_bf16(acc[i][j][r] * inv, ph, pl);
                P_hi[ob + j * 16] = ph;
                P_lo[ob + j * 16] = pl;
            }
        }
    }
}

// ---------------------------------------------------------------------------
// Workspace (bytes), peak exactly 120,094,720:
//   Wo_sp   [0, 6,553,600)                   live to Mh
//   kv_sp   [6,553,600, 19,169,280)          kv-gemm -> Mh
//   Wkv_sp  [19,169,280, 29,655,040)         dead after kv-gemm
//   Nbig_sp [19,169,280, 71,598,080)         Nh -> S-fused (over Wkv)
//   MbT_sp  [19,169,280, 71,598,080)         Mh -> o-gemm (over dead Nbig)
//   WqT_sp  [71,598,080, 78,151,680)         dead after Nh
//   enc_sp  [78,151,680, 83,197,952)         dead after kv-gemm
//   P_sp    [78,151,680, 120,094,720)        S-fused -> o-gemm (over WqT/enc)
// hidden splits live in d_out until the final o-gemm overwrites it.
// Order: folds -> splits -> kv -> Nh -> S-fused(P) -> Mh -> o.
// ---------------------------------------------------------------------------
extern "C" void kernel_launch(void* const* d_in, const int* in_sizes, int n_in,
                              void* d_out, int out_size, void* d_ws, size_t ws_size,
                              hipStream_t stream) {
    const float* hidden = (const float*)d_in[0];
    const float* enc    = (const float*)d_in[1];
    const float* Wq     = (const float*)d_in[2];
    const float* Wk     = (const float*)d_in[3];
    const float* Wv     = (const float*)d_in[4];
    const float* Wo     = (const float*)d_in[5];
    const float* bo     = (const float*)d_in[6];
    const float* q_down = (const float*)d_in[7];
    const float* q_up   = (const float*)d_in[8];
    const float* k_down = (const float*)d_in[9];
    const float* k_up   = (const float*)d_in[10];
    const float* v_down = (const float*)d_in[11];
    const float* v_up   = (const float*)d_in[12];
    const float* o_down = (const float*)d_in[13];
    const float* o_up   = (const float*)d_in[14];

    char* ws = (char*)d_ws;
    unsigned short* Wo_hi   = (unsigned short*)(ws);
    unsigned short* Wo_lo   = (unsigned short*)(ws + 3276800);
    unsigned short* kv_hi   = (unsigned short*)(ws + 6553600);
    unsigned short* kv_lo   = (unsigned short*)(ws + 12861440);
    unsigned short* Wkv_hi  = (unsigned short*)(ws + 19169280);
    unsigned short* Wkv_lo  = (unsigned short*)(ws + 24412160);
    unsigned short* Nbig_hi = (unsigned short*)(ws + 19169280);
    unsigned short* Nbig_lo = (unsigned short*)(ws + 45383680);
    unsigned short* MbT_hi  = (unsigned short*)(ws + 19169280);
    unsigned short* MbT_lo  = (unsigned short*)(ws + 45383680);
    unsigned short* WqT_hi  = (unsigned short*)(ws + 71598080);
    unsigned short* WqT_lo  = (unsigned short*)(ws + 74874880);
    unsigned short* enc_hi  = (unsigned short*)(ws + 78151680);
    unsigned short* enc_lo  = (unsigned short*)(ws + 80674816);
    unsigned short* P_hi    = (unsigned short*)(ws + 78151680);
    unsigned short* P_lo    = (unsigned short*)(ws + 99123200);
    unsigned short* hid_hi  = (unsigned short*)d_out;
    unsigned short* hid_lo  = hid_hi + (size_t)20971520;

    const int M1 = BB * SQ;    // 16384
    const int M2 = BB * SENC;  // 1232

    dim3 blk(256);
    // ---- weight prep ----
    fold_split_kernel<<<1600, blk, 0, stream>>>(Wo, o_up, o_down, Wo_hi, Wo_lo, CC, CC);
    foldT_split_kernel<<<dim3(40, 40), blk, 0, stream>>>(Wq, q_up, q_down, WqT_hi, WqT_lo);
    fold_split_kv_kernel<<<2560, blk, 0, stream>>>(Wk, Wv, k_up, k_down, v_up, v_down,
                                                   Wkv_hi, Wkv_lo);
    // ---- activation splits ----
    split_kernel<<<1232, blk, 0, stream>>>(enc, enc_hi, enc_lo, (M2 * CENC) / 4);
    split_kernel<<<20480, blk, 0, stream>>>(hidden, hid_hi, hid_lo, (M1 * CC) / 4);

    // ---- kv = enc @ [Wk|Wv]_eff^T -> kv splits [1232][2560] ----
    gemm2_kernel<0><<<dim3(20, 10), blk, 0, stream>>>(
        enc_hi, enc_lo, CENC, Wkv_hi, Wkv_lo, CENC,
        nullptr, nullptr, kv_hi, kv_lo, 2560, M2, 2560, CENC);

    // ---- Nh[b,h] = K_h[b] @ Wq_h -> Nbig splits [16][640][1280] ----
    gemm2_kernel<1><<<dim3(10, 1, 128), blk, 0, stream>>>(
        kv_hi, kv_lo, 2560, WqT_hi, WqT_lo, CC,
        nullptr, nullptr, Nbig_hi, Nbig_lo, CC, SENC, CC, DH);

    // ---- S = hidden @ Nbig[b]^T, fused softmax -> P splits [16384][640] ----
    sgemm_softmax_kernel<<<512, blk, 0, stream>>>(
        hid_hi, hid_lo, Nbig_hi, Nbig_lo, P_hi, P_lo);

    // ---- MhT[b,h] = Wo_eff[:,h] @ V_h[b]^T -> MbT splits [16][1280][640] ----
    gemm2_kernel<2><<<dim3(1, 10, 128), blk, 0, stream>>>(
        Wo_hi, Wo_lo, CC, kv_hi, kv_lo, 2560,
        nullptr, nullptr, MbT_hi, MbT_lo, 640, CC, SENC, DH);

    // ---- out = P @ MbT[b]^T + bo -> fp32 d_out ----
    gemm2_kernel<4><<<1280, blk, 0, stream>>>(
        P_hi, P_lo, 640, MbT_hi, MbT_lo, 640,
        bo, (float*)d_out, nullptr, nullptr, CC, M1, CC, 640);
}

// Round 7
// 461.056 us; speedup vs baseline: 4.3492x; 1.0512x over previous
//
#include <hip/hip_runtime.h>

// Problem constants
#define NH    8
#define BB    16
#define SQ    1024
#define CC    1280
#define SENC  77
#define CENC  1024
#define DH    160
#define RANK  4

typedef __attribute__((ext_vector_type(8))) short bf16x8;
typedef __attribute__((ext_vector_type(4))) float f32x4;

// ---------------------------------------------------------------------------
// fp32 -> bf16 hi/lo split (truncation; hi+lo captures ~16 mantissa bits)
// ---------------------------------------------------------------------------
__device__ inline void split_bf16(float a, unsigned short& hi, unsigned short& lo) {
    unsigned u = __float_as_uint(a);
    hi = (unsigned short)(u >> 16);
    float fhi = __uint_as_float(u & 0xffff0000u);
    float r = a - fhi;
    lo = (unsigned short)(__float_as_uint(r) >> 16);
}

__device__ inline void split_store4(float4 a, unsigned short* ohi,
                                    unsigned short* olo, int i) {
    unsigned short h0, h1, h2, h3, l0, l1, l2, l3;
    split_bf16(a.x, h0, l0); split_bf16(a.y, h1, l1);
    split_bf16(a.z, h2, l2); split_bf16(a.w, h3, l3);
    int2 hv, lv;
    hv.x = (int)((unsigned)h0 | ((unsigned)h1 << 16));
    hv.y = (int)((unsigned)h2 | ((unsigned)h3 << 16));
    lv.x = (int)((unsigned)l0 | ((unsigned)l1 << 16));
    lv.y = (int)((unsigned)l2 | ((unsigned)l3 << 16));
    *(int2*)(ohi + i) = hv;
    *(int2*)(olo + i) = lv;
}

// fold helper: Weff row-element group of 4
__device__ inline float4 fold4(const float* W, const float* up, const float* down,
                               int n, int kk, int K) {
    float4 acc = *(const float4*)(W + (size_t)n * K + kk);
#pragma unroll
    for (int r = 0; r < RANK; ++r) {
        float u = up[n * RANK + r];
        float4 dv = *(const float4*)(down + (size_t)r * K + kk);
        acc.x += u * dv.x; acc.y += u * dv.y;
        acc.z += u * dv.z; acc.w += u * dv.w;
    }
    return acc;
}

// ---------------------------------------------------------------------------
// Mega prep kernel: all weight folds + activation splits in ONE launch.
//   [0,1600)      Wo fold+split
//   [1600,3200)   Wq fold+transpose+split (LDS 32x33 tiles)
//   [3200,5760)   Wk|Wv fold+split into [2560][1024]
//   [5760,6992)   enc split
//   [6992,27472)  hidden split
// ---------------------------------------------------------------------------
__global__ __launch_bounds__(256) void prep_kernel(
    const float* __restrict__ hidden, const float* __restrict__ enc,
    const float* __restrict__ Wq, const float* __restrict__ Wk,
    const float* __restrict__ Wv, const float* __restrict__ Wo,
    const float* __restrict__ q_up, const float* __restrict__ q_down,
    const float* __restrict__ k_up, const float* __restrict__ k_down,
    const float* __restrict__ v_up, const float* __restrict__ v_down,
    const float* __restrict__ o_up, const float* __restrict__ o_down,
    unsigned short* __restrict__ Wo_hi, unsigned short* __restrict__ Wo_lo,
    unsigned short* __restrict__ WqT_hi, unsigned short* __restrict__ WqT_lo,
    unsigned short* __restrict__ Wkv_hi, unsigned short* __restrict__ Wkv_lo,
    unsigned short* __restrict__ enc_hi, unsigned short* __restrict__ enc_lo,
    unsigned short* __restrict__ hid_hi, unsigned short* __restrict__ hid_lo) {
    __shared__ float t[32][33];
    const int bid = blockIdx.x;
    const int tid = threadIdx.x;

    if (bid < 1600) {                      // ---- Wo fold + split ----
        int idx4 = bid * 256 + tid;
        int i = idx4 << 2;
        int n = i / CC, kk = i - n * CC;
        split_store4(fold4(Wo, o_up, o_down, n, kk, CC), Wo_hi, Wo_lo, i);
    } else if (bid < 3200) {               // ---- Wq fold + transpose + split ----
        int b2 = bid - 1600;
        int bx = b2 % 40, by = b2 / 40;
        int tx = tid & 31, ty = tid >> 5;
        int k = bx * 32 + tx;
#pragma unroll
        for (int r4 = 0; r4 < 4; ++r4) {
            int n = by * 32 + ty + 8 * r4;
            float v = Wq[(size_t)n * 1280 + k];
#pragma unroll
            for (int r = 0; r < RANK; ++r)
                v += q_up[n * RANK + r] * q_down[r * 1280 + k];
            t[ty + 8 * r4][tx] = v;
        }
        __syncthreads();
#pragma unroll
        for (int r4 = 0; r4 < 4; ++r4) {
            float v = t[tx][ty + 8 * r4];
            unsigned short h_, l_;
            split_bf16(v, h_, l_);
            size_t o = (size_t)(bx * 32 + ty + 8 * r4) * 1280 + by * 32 + tx;
            WqT_hi[o] = h_; WqT_lo[o] = l_;
        }
    } else if (bid < 5760) {               // ---- Wk|Wv fold + split ----
        int idx4 = (bid - 3200) * 256 + tid;
        int i = idx4 << 2;
        int n = i >> 10, kk = i & 1023;
        float4 v;
        if (n < CC) v = fold4(Wk, k_up, k_down, n, kk, CENC);
        else        v = fold4(Wv, v_up, v_down, n - CC, kk, CENC);
        split_store4(v, Wkv_hi, Wkv_lo, i);
    } else if (bid < 6992) {               // ---- enc split ----
        int idx4 = (bid - 5760) * 256 + tid;
        int i = idx4 << 2;
        split_store4(*(const float4*)(enc + i), enc_hi, enc_lo, i);
    } else {                               // ---- hidden split ----
        int idx4 = (bid - 6992) * 256 + tid;
        int i = idx4 << 2;
        split_store4(*(const float4*)(hidden + i), hid_hi, hid_lo, i);
    }
}

// ---------------------------------------------------------------------------
// Generalized MFMA split-bf16 GEMM (proven 128x128/BK=32/4-wave inner loop)
// MODE 0 kv | MODE 4 o-proj (T1 bijective swizzle, bias)
// ---------------------------------------------------------------------------
#define GBM 128
#define GBN 128
#define GBK 32

__device__ inline void async_load16(const void* gsrc, void* lds_dst) {
    __builtin_amdgcn_global_load_lds(
        (const __attribute__((address_space(1))) void*)gsrc,
        (__attribute__((address_space(3))) void*)lds_dst, 16, 0, 0);
}

__device__ inline int clampi(int x, int hi) { return x > hi ? hi : x; }

template <int MODE>
__global__ __launch_bounds__(256) void gemm2_kernel(
    const unsigned short* __restrict__ A_hi, const unsigned short* __restrict__ A_lo,
    int lda,
    const unsigned short* __restrict__ W_hi, const unsigned short* __restrict__ W_lo,
    int ldw,
    const float* __restrict__ bias, float* __restrict__ outF,
    unsigned short* __restrict__ oHi, unsigned short* __restrict__ oLo, int ldo,
    int M, int N, int K) {
    __shared__ __align__(16) unsigned short lds[4][GBM][GBK];
    const int tid  = threadIdx.x;
    const int wave = tid >> 6;
    const int lane = tid & 63;

    int m0, n0;
    if constexpr (MODE == 0) {
        n0 = blockIdx.x * GBN; m0 = blockIdx.y * GBM;
    } else {
        int bid = blockIdx.x;                       // 1280 blocks, T1 bijective
        int w = (bid & 7) * 160 + (bid >> 3);
        int mt = w / 10, nt = w - mt * 10;
        m0 = mt * GBM; n0 = nt * GBN;
        int b = m0 >> 10;
        size_t wo = (size_t)b * CC * ldw;
        W_hi += wo; W_lo += wo;
    }

    const int wr = wave >> 1, wc = wave & 1;
    f32x4 zero = {0.f, 0.f, 0.f, 0.f};
    f32x4 acc[4][4];
#pragma unroll
    for (int i = 0; i < 4; ++i)
#pragma unroll
        for (int j = 0; j < 4; ++j) acc[i][j] = zero;

    const int c0 = wave * 2, c1 = wave * 2 + 1;
    const int rr = lane >> 2;
    const int kc = (lane & 3) * 8;
    const int ra0 = clampi(m0 + c0 * 16 + rr, M - 1);
    const int ra1 = clampi(m0 + c1 * 16 + rr, M - 1);
    const int rw0 = clampi(n0 + c0 * 16 + rr, N - 1);
    const int rw1 = clampi(n0 + c1 * 16 + rr, N - 1);
    const unsigned short* pAh0 = A_hi + (size_t)ra0 * lda + kc;
    const unsigned short* pAh1 = A_hi + (size_t)ra1 * lda + kc;
    const unsigned short* pAl0 = A_lo + (size_t)ra0 * lda + kc;
    const unsigned short* pAl1 = A_lo + (size_t)ra1 * lda + kc;
    const unsigned short* pWh0 = W_hi + (size_t)rw0 * ldw + kc;
    const unsigned short* pWh1 = W_hi + (size_t)rw1 * ldw + kc;
    const unsigned short* pWl0 = W_lo + (size_t)rw0 * ldw + kc;
    const unsigned short* pWl1 = W_lo + (size_t)rw1 * ldw + kc;

    for (int k0 = 0; k0 < K; k0 += GBK) {
        async_load16(pAh0 + k0, &lds[0][c0 * 16][0]);
        async_load16(pAh1 + k0, &lds[0][c1 * 16][0]);
        async_load16(pAl0 + k0, &lds[1][c0 * 16][0]);
        async_load16(pAl1 + k0, &lds[1][c1 * 16][0]);
        async_load16(pWh0 + k0, &lds[2][c0 * 16][0]);
        async_load16(pWh1 + k0, &lds[2][c1 * 16][0]);
        async_load16(pWl0 + k0, &lds[3][c0 * 16][0]);
        async_load16(pWl1 + k0, &lds[3][c1 * 16][0]);
        __syncthreads();

        bf16x8 ah[4], al[4], bh[4], bl[4];
        const int fr = lane & 15;
        const int kb = (lane >> 4) * 8;
#pragma unroll
        for (int i = 0; i < 4; ++i) {
            ah[i] = *(const bf16x8*)&lds[0][wr * 64 + i * 16 + fr][kb];
            al[i] = *(const bf16x8*)&lds[1][wr * 64 + i * 16 + fr][kb];
            bh[i] = *(const bf16x8*)&lds[2][wc * 64 + i * 16 + fr][kb];
            bl[i] = *(const bf16x8*)&lds[3][wc * 64 + i * 16 + fr][kb];
        }
#pragma unroll
        for (int i = 0; i < 4; ++i)
#pragma unroll
            for (int j = 0; j < 4; ++j) {
                acc[i][j] = __builtin_amdgcn_mfma_f32_16x16x32_bf16(ah[i], bh[j], acc[i][j], 0, 0, 0);
                acc[i][j] = __builtin_amdgcn_mfma_f32_16x16x32_bf16(ah[i], bl[j], acc[i][j], 0, 0, 0);
                acc[i][j] = __builtin_amdgcn_mfma_f32_16x16x32_bf16(al[i], bh[j], acc[i][j], 0, 0, 0);
            }
        __syncthreads();
    }

    // C/D layout: col=lane&15, row=(lane>>4)*4+reg  [m89-verified]
    const int fc = lane & 15;
    const int fr4 = (lane >> 4) * 4;
#pragma unroll
    for (int j = 0; j < 4; ++j) {
        int col = n0 + wc * 64 + j * 16 + fc;
        float bv = 0.f;
        if constexpr (MODE == 4) bv = bias[col];
#pragma unroll
        for (int i = 0; i < 4; ++i) {
            int row = m0 + wr * 64 + i * 16 + fr4;
#pragma unroll
            for (int r = 0; r < 4; ++r) {
                int rowr = row + r;
                float val = acc[i][j][r];
                if constexpr (MODE == 0) {
                    if (rowr < M) {
                        unsigned short vh, vl;
                        split_bf16(val, vh, vl);
                        oHi[(size_t)rowr * ldo + col] = vh;
                        oLo[(size_t)rowr * ldo + col] = vl;
                    }
                } else {
                    outF[(size_t)rowr * ldo + col] = val + bv;
                }
            }
        }
    }
}

// ---------------------------------------------------------------------------
// Nh kernel (de-padded): per (b,h) computes Nbig rows h*80+(0..79), 80x128 tile.
// grid (10 nt, 128 z). Waves: 4 x (80 rows x 32 cols), frags 5x2.
// LDS (shorts): Ah@0[80x32] Al@2560 Wh@5120[128x32] Wl@9216; 26 chunks of 1KB.
// ---------------------------------------------------------------------------
__global__ __launch_bounds__(256) void nh_kernel(
    const unsigned short* __restrict__ kv_hi, const unsigned short* __restrict__ kv_lo,
    const unsigned short* __restrict__ WqT_hi, const unsigned short* __restrict__ WqT_lo,
    unsigned short* __restrict__ oHi, unsigned short* __restrict__ oLo) {
    __shared__ __align__(16) unsigned short sL[13312];
    const int tid = threadIdx.x, wave = tid >> 6, lane = tid & 63;
    const int fr = lane & 15, g = lane >> 4, kb = g * 8;
    const int n0 = blockIdx.x * 128;
    const int z = blockIdx.y, b = z >> 3, h = z & 7;

    const unsigned short* Abh = kv_hi + (size_t)(b * SENC) * 2560 + h * DH;
    const unsigned short* Abl = kv_lo + (size_t)(b * SENC) * 2560 + h * DH;
    const unsigned short* Wbh = WqT_hi + h * DH;
    const unsigned short* Wbl = WqT_lo + h * DH;

    const int rr = lane >> 2;
    const int kc = (lane & 3) * 8;
    const unsigned short* gsrc[7];
    char* gdst[7];
    bool gok[7];
#pragma unroll
    for (int q = 0; q < 7; ++q) {
        int c = wave * 7 + q;
        gok[q] = (c < 26);
        int cc = gok[q] ? c : 25;
        const unsigned short* src; int dst;
        if (cc < 5)       { src = Abh + (size_t)clampi(cc * 16 + rr, 76) * 2560 + kc; dst = cc * 1024; }
        else if (cc < 10) { src = Abl + (size_t)clampi((cc - 5) * 16 + rr, 76) * 2560 + kc; dst = 5120 + (cc - 5) * 1024; }
        else if (cc < 18) { src = Wbh + (size_t)(n0 + (cc - 10) * 16 + rr) * 1280 + kc; dst = 10240 + (cc - 10) * 1024; }
        else              { src = Wbl + (size_t)(n0 + (cc - 18) * 16 + rr) * 1280 + kc; dst = 18432 + (cc - 18) * 1024; }
        gsrc[q] = src; gdst[q] = (char*)sL + dst;
    }

    f32x4 zero = {0.f, 0.f, 0.f, 0.f};
    f32x4 acc[5][2];
#pragma unroll
    for (int i = 0; i < 5; ++i)
#pragma unroll
        for (int j = 0; j < 2; ++j) acc[i][j] = zero;

    for (int k0 = 0; k0 < DH; k0 += 32) {
#pragma unroll
        for (int q = 0; q < 7; ++q)
            if (gok[q]) async_load16(gsrc[q] + k0, gdst[q]);
        __syncthreads();

        bf16x8 ah[5], al[5], wh[2], wl[2];
#pragma unroll
        for (int i = 0; i < 5; ++i) {
            ah[i] = *(const bf16x8*)&sL[(i * 16 + fr) * 32 + kb];
            al[i] = *(const bf16x8*)&sL[2560 + (i * 16 + fr) * 32 + kb];
        }
#pragma unroll
        for (int j = 0; j < 2; ++j) {
            wh[j] = *(const bf16x8*)&sL[5120 + (wave * 32 + j * 16 + fr) * 32 + kb];
            wl[j] = *(const bf16x8*)&sL[9216 + (wave * 32 + j * 16 + fr) * 32 + kb];
        }
#pragma unroll
        for (int i = 0; i < 5; ++i)
#pragma unroll
            for (int j = 0; j < 2; ++j) {
                acc[i][j] = __builtin_amdgcn_mfma_f32_16x16x32_bf16(ah[i], wh[j], acc[i][j], 0, 0, 0);
                acc[i][j] = __builtin_amdgcn_mfma_f32_16x16x32_bf16(ah[i], wl[j], acc[i][j], 0, 0, 0);
                acc[i][j] = __builtin_amdgcn_mfma_f32_16x16x32_bf16(al[i], wh[j], acc[i][j], 0, 0, 0);
            }
        __syncthreads();
    }

    const int fc = lane & 15;
    const int fr4 = (lane >> 4) * 4;
    const size_t obase = (size_t)(b * 640 + h * 80) * 1280;
#pragma unroll
    for (int i = 0; i < 5; ++i)
#pragma unroll
        for (int j = 0; j < 2; ++j)
#pragma unroll
            for (int r = 0; r < 4; ++r) {
                int row = i * 16 + fr4 + r;
                int col = n0 + wave * 32 + j * 16 + fc;
                float v = (row >= SENC) ? 0.f : acc[i][j][r];
                unsigned short vh, vl;
                split_bf16(v, vh, vl);
                oHi[obase + (size_t)row * 1280 + col] = vh;
                oLo[obase + (size_t)row * 1280 + col] = vl;
            }
}

// ---------------------------------------------------------------------------
// Mh kernel (de-padded): per (b,h) computes MbT rows m0..m0+127, cols h*80+(0..79).
// grid (10 mt, 128 z). Waves: 4 x (32 rows x 80 cols), frags 2x5.
// LDS (shorts): Ah@0[128x32] Al@4096 Wh@8192[80x32] Wl@10752; 26 chunks.
// ---------------------------------------------------------------------------
__global__ __launch_bounds__(256) void mh_kernel(
    const unsigned short* __restrict__ Wo_hi, const unsigned short* __restrict__ Wo_lo,
    const unsigned short* __restrict__ kv_hi, const unsigned short* __restrict__ kv_lo,
    unsigned short* __restrict__ oHi, unsigned short* __restrict__ oLo) {
    __shared__ __align__(16) unsigned short sL[13312];
    const int tid = threadIdx.x, wave = tid >> 6, lane = tid & 63;
    const int fr = lane & 15, g = lane >> 4, kb = g * 8;
    const int m0 = blockIdx.x * 128;
    const int z = blockIdx.y, b = z >> 3, h = z & 7;

    const unsigned short* Abh = Wo_hi + h * DH;
    const unsigned short* Abl = Wo_lo + h * DH;
    const unsigned short* Wbh = kv_hi + (size_t)(b * SENC) * 2560 + CC + h * DH;
    const unsigned short* Wbl = kv_lo + (size_t)(b * SENC) * 2560 + CC + h * DH;

    const int rr = lane >> 2;
    const int kc = (lane & 3) * 8;
    const unsigned short* gsrc[7];
    char* gdst[7];
    bool gok[7];
#pragma unroll
    for (int q = 0; q < 7; ++q) {
        int c = wave * 7 + q;
        gok[q] = (c < 26);
        int cc = gok[q] ? c : 25;
        const unsigned short* src; int dst;
        if (cc < 8)       { src = Abh + (size_t)(m0 + cc * 16 + rr) * 1280 + kc; dst = cc * 1024; }
        else if (cc < 16) { src = Abl + (size_t)(m0 + (cc - 8) * 16 + rr) * 1280 + kc; dst = 8192 + (cc - 8) * 1024; }
        else if (cc < 21) { src = Wbh + (size_t)clampi((cc - 16) * 16 + rr, 76) * 2560 + kc; dst = 16384 + (cc - 16) * 1024; }
        else              { src = Wbl + (size_t)clampi((cc - 21) * 16 + rr, 76) * 2560 + kc; dst = 21504 + (cc - 21) * 1024; }
        gsrc[q] = src; gdst[q] = (char*)sL + dst;
    }

    f32x4 zero = {0.f, 0.f, 0.f, 0.f};
    f32x4 acc[2][5];
#pragma unroll
    for (int i = 0; i < 2; ++i)
#pragma unroll
        for (int j = 0; j < 5; ++j) acc[i][j] = zero;

    for (int k0 = 0; k0 < DH; k0 += 32) {
#pragma unroll
        for (int q = 0; q < 7; ++q)
            if (gok[q]) async_load16(gsrc[q] + k0, gdst[q]);
        __syncthreads();

        bf16x8 ah[2], al[2], wh[5], wl[5];
#pragma unroll
        for (int i = 0; i < 2; ++i) {
            ah[i] = *(const bf16x8*)&sL[(wave * 32 + i * 16 + fr) * 32 + kb];
            al[i] = *(const bf16x8*)&sL[4096 + (wave * 32 + i * 16 + fr) * 32 + kb];
        }
#pragma unroll
        for (int j = 0; j < 5; ++j) {
            wh[j] = *(const bf16x8*)&sL[8192 + (j * 16 + fr) * 32 + kb];
            wl[j] = *(const bf16x8*)&sL[10752 + (j * 16 + fr) * 32 + kb];
        }
#pragma unroll
        for (int i = 0; i < 2; ++i)
#pragma unroll
            for (int j = 0; j < 5; ++j) {
                acc[i][j] = __builtin_amdgcn_mfma_f32_16x16x32_bf16(ah[i], wh[j], acc[i][j], 0, 0, 0);
                acc[i][j] = __builtin_amdgcn_mfma_f32_16x16x32_bf16(ah[i], wl[j], acc[i][j], 0, 0, 0);
                acc[i][j] = __builtin_amdgcn_mfma_f32_16x16x32_bf16(al[i], wh[j], acc[i][j], 0, 0, 0);
            }
        __syncthreads();
    }

    const int fc = lane & 15;
    const int fr4 = (lane >> 4) * 4;
    const size_t obase = (size_t)b * CC * 640 + h * 80;
#pragma unroll
    for (int i = 0; i < 2; ++i)
#pragma unroll
        for (int j = 0; j < 5; ++j)
#pragma unroll
            for (int r = 0; r < 4; ++r) {
                int row = m0 + wave * 32 + i * 16 + fr4 + r;
                int col = j * 16 + fc;
                float v = (col >= SENC) ? 0.f : acc[i][j][r];
                unsigned short vh, vl;
                split_bf16(v, vh, vl);
                oHi[obase + (size_t)row * 640 + col] = vh;
                oLo[obase + (size_t)row * 640 + col] = vl;
            }
}

// ---------------------------------------------------------------------------
// Fused S-GEMM + softmax -> P splits (unchanged from round 6, proven).
// ---------------------------------------------------------------------------
__global__ __launch_bounds__(256) void sgemm_softmax_kernel(
    const unsigned short* __restrict__ A_hi, const unsigned short* __restrict__ A_lo,
    const unsigned short* __restrict__ Nbig_hi, const unsigned short* __restrict__ Nbig_lo,
    unsigned short* __restrict__ P_hi, unsigned short* __restrict__ P_lo) {
    __shared__ __align__(16) unsigned short sLDS[18432];
    const int tid = threadIdx.x;
    const int wave = tid >> 6;
    const int lane = tid & 63;
    const int fr = lane & 15;
    const int g = lane >> 4;
    const float scale = 0.07905694150420949f;  // 1/sqrt(160)

    int bid = blockIdx.x;                      // 512 blocks
    int w = (bid & 7) * 64 + (bid >> 3);       // T1 bijective (512 % 8 == 0)
    int mt = w >> 2, nt = w & 3;
    const int m0 = mt * 128;
    const int n0 = nt * 160;
    const int b = mt >> 3;
    const unsigned short* W_hi = Nbig_hi + (size_t)b * 640 * CC;
    const unsigned short* W_lo = Nbig_lo + (size_t)b * 640 * CC;

    const int wr = wave >> 1, wc = wave & 1;

    const int rr = lane >> 2;
    const int kcs = ((lane & 3) ^ ((lane >> 3) & 3)) * 8;   // swizzled src k-group
    const unsigned short* gsrc[9];
    int ldst[9];
#pragma unroll
    for (int q = 0; q < 9; ++q) {
        int c = wave * 9 + q;
        const unsigned short* base; int ld, row0, toff, lc;
        if (c < 8)       { base = A_hi; ld = CC; row0 = m0; toff = 0;     lc = c; }
        else if (c < 16) { base = A_lo; ld = CC; row0 = m0; toff = 4096;  lc = c - 8; }
        else if (c < 26) { base = W_hi; ld = CC; row0 = n0; toff = 8192;  lc = c - 16; }
        else             { base = W_lo; ld = CC; row0 = n0; toff = 13312; lc = c - 26; }
        gsrc[q] = base + (size_t)(row0 + lc * 16 + rr) * ld + kcs;
        ldst[q] = toff + lc * 512;
    }

    f32x4 zero = {0.f, 0.f, 0.f, 0.f};
    f32x4 acc[4][5];
#pragma unroll
    for (int i = 0; i < 4; ++i)
#pragma unroll
        for (int j = 0; j < 5; ++j) acc[i][j] = zero;

    const int kbsw = (g ^ ((fr >> 1) & 3)) * 8;  // swizzled read k-group

    for (int k0 = 0; k0 < CC; k0 += 32) {
#pragma unroll
        for (int q = 0; q < 9; ++q)
            async_load16(gsrc[q] + k0, &sLDS[ldst[q]]);
        __syncthreads();

        bf16x8 ah[4], al[4];
#pragma unroll
        for (int i = 0; i < 4; ++i) {
            int r = wr * 64 + i * 16 + fr;
            ah[i] = *(const bf16x8*)&sLDS[r * 32 + kbsw];
            al[i] = *(const bf16x8*)&sLDS[4096 + r * 32 + kbsw];
        }
#pragma unroll
        for (int j = 0; j < 5; ++j) {
            int rb = wc * 80 + j * 16 + fr;
            bf16x8 bh = *(const bf16x8*)&sLDS[8192 + rb * 32 + kbsw];
            bf16x8 bl = *(const bf16x8*)&sLDS[13312 + rb * 32 + kbsw];
#pragma unroll
            for (int i = 0; i < 4; ++i) {
                acc[i][j] = __builtin_amdgcn_mfma_f32_16x16x32_bf16(ah[i], bh, acc[i][j], 0, 0, 0);
                acc[i][j] = __builtin_amdgcn_mfma_f32_16x16x32_bf16(ah[i], bl, acc[i][j], 0, 0, 0);
                acc[i][j] = __builtin_amdgcn_mfma_f32_16x16x32_bf16(al[i], bh, acc[i][j], 0, 0, 0);
            }
        }
        __syncthreads();
    }

    const int fc = fr;
    const bool maskme = (fc >= 13);  // j==4 frag: cols 77..79
#pragma unroll
    for (int i = 0; i < 4; ++i) {
#pragma unroll
        for (int r = 0; r < 4; ++r) {
            float m = -1e30f;
#pragma unroll
            for (int j = 0; j < 5; ++j) {
                float v = acc[i][j][r] * scale;
                if (j == 4 && maskme) v = -1e30f;
                acc[i][j][r] = v;
                m = fmaxf(m, v);
            }
#pragma unroll
            for (int msk = 1; msk < 16; msk <<= 1) m = fmaxf(m, __shfl_xor(m, msk));
            float sum = 0.f;
#pragma unroll
            for (int j = 0; j < 5; ++j) {
                float e = (j == 4 && maskme) ? 0.f : __expf(acc[i][j][r] - m);
                acc[i][j][r] = e;
                sum += e;
            }
#pragma unroll
            for (int msk = 1; msk < 16; msk <<= 1) sum += __shfl_xor(sum, msk);
            float inv = 1.f / sum;
            int row = m0 + wr * 64 + i * 16 + g * 4 + r;
            size_t ob = (size_t)row * 640 + n0 + wc * 80 + fc;
#pragma unroll
            for (int j = 0; j < 5; ++j) {
                unsigned short ph, pl;
                split_bf16(acc[i][j][r] * inv, ph, pl);
                P_hi[ob + j * 16] = ph;
                P_lo[ob + j * 16] = pl;
            }
        }
    }
}

// ---------------------------------------------------------------------------
// Workspace (unchanged round-6 map, peak 120,094,720):
//   Wo_sp [0,6.55M) | kv_sp [6.55M,19.17M) | Wkv/Nbig/MbT overlay [19.17M,71.6M)
//   WqT [71.6M,78.15M) | enc/P overlay [78.15M,120.09M)
// hidden splits live in d_out until the final o-gemm overwrites it.
// Order: prep -> kv -> Nh -> S-fused -> Mh -> o   (6 launches)
// ---------------------------------------------------------------------------
extern "C" void kernel_launch(void* const* d_in, const int* in_sizes, int n_in,
                              void* d_out, int out_size, void* d_ws, size_t ws_size,
                              hipStream_t stream) {
    const float* hidden = (const float*)d_in[0];
    const float* enc    = (const float*)d_in[1];
    const float* Wq     = (const float*)d_in[2];
    const float* Wk     = (const float*)d_in[3];
    const float* Wv     = (const float*)d_in[4];
    const float* Wo     = (const float*)d_in[5];
    const float* bo     = (const float*)d_in[6];
    const float* q_down = (const float*)d_in[7];
    const float* q_up   = (const float*)d_in[8];
    const float* k_down = (const float*)d_in[9];
    const float* k_up   = (const float*)d_in[10];
    const float* v_down = (const float*)d_in[11];
    const float* v_up   = (const float*)d_in[12];
    const float* o_down = (const float*)d_in[13];
    const float* o_up   = (const float*)d_in[14];

    char* ws = (char*)d_ws;
    unsigned short* Wo_hi   = (unsigned short*)(ws);
    unsigned short* Wo_lo   = (unsigned short*)(ws + 3276800);
    unsigned short* kv_hi   = (unsigned short*)(ws + 6553600);
    unsigned short* kv_lo   = (unsigned short*)(ws + 12861440);
    unsigned short* Wkv_hi  = (unsigned short*)(ws + 19169280);
    unsigned short* Wkv_lo  = (unsigned short*)(ws + 24412160);
    unsigned short* Nbig_hi = (unsigned short*)(ws + 19169280);
    unsigned short* Nbig_lo = (unsigned short*)(ws + 45383680);
    unsigned short* MbT_hi  = (unsigned short*)(ws + 19169280);
    unsigned short* MbT_lo  = (unsigned short*)(ws + 45383680);
    unsigned short* WqT_hi  = (unsigned short*)(ws + 71598080);
    unsigned short* WqT_lo  = (unsigned short*)(ws + 74874880);
    unsigned short* enc_hi  = (unsigned short*)(ws + 78151680);
    unsigned short* enc_lo  = (unsigned short*)(ws + 80674816);
    unsigned short* P_hi    = (unsigned short*)(ws + 78151680);
    unsigned short* P_lo    = (unsigned short*)(ws + 99123200);
    unsigned short* hid_hi  = (unsigned short*)d_out;
    unsigned short* hid_lo  = hid_hi + (size_t)20971520;

    const int M1 = BB * SQ;    // 16384
    const int M2 = BB * SENC;  // 1232

    dim3 blk(256);
    // ---- all folds + splits, one launch ----
    prep_kernel<<<27472, blk, 0, stream>>>(
        hidden, enc, Wq, Wk, Wv, Wo, q_up, q_down, k_up, k_down,
        v_up, v_down, o_up, o_down,
        Wo_hi, Wo_lo, WqT_hi, WqT_lo, Wkv_hi, Wkv_lo,
        enc_hi, enc_lo, hid_hi, hid_lo);

    // ---- kv = enc @ [Wk|Wv]_eff^T -> kv splits [1232][2560] ----
    gemm2_kernel<0><<<dim3(20, 10), blk, 0, stream>>>(
        enc_hi, enc_lo, CENC, Wkv_hi, Wkv_lo, CENC,
        nullptr, nullptr, kv_hi, kv_lo, 2560, M2, 2560, CENC);

    // ---- Nh[b,h] = K_h[b] @ Wq_h -> Nbig splits [16][640][1280] ----
    nh_kernel<<<dim3(10, 128), blk, 0, stream>>>(
        kv_hi, kv_lo, WqT_hi, WqT_lo, Nbig_hi, Nbig_lo);

    // ---- S = hidden @ Nbig[b]^T, fused softmax -> P splits [16384][640] ----
    sgemm_softmax_kernel<<<512, blk, 0, stream>>>(
        hid_hi, hid_lo, Nbig_hi, Nbig_lo, P_hi, P_lo);

    // ---- MhT[b,h] = Wo_eff[:,h] @ V_h[b]^T -> MbT splits [16][1280][640] ----
    mh_kernel<<<dim3(10, 128), blk, 0, stream>>>(
        Wo_hi, Wo_lo, kv_hi, kv_lo, MbT_hi, MbT_lo);

    // ---- out = P @ MbT[b]^T + bo -> fp32 d_out ----
    gemm2_kernel<4><<<1280, blk, 0, stream>>>(
        P_hi, P_lo, 640, MbT_hi, MbT_lo, 640,
        bo, (float*)d_out, nullptr, nullptr, CC, M1, CC, 640);
}